// Round 1
// baseline (601.382 us; speedup 1.0000x reference)
//
#include <hip/hip_runtime.h>

// Problem constants
#define BB   2
#define SS   2048
#define TT   4096      // B*S
#define HH   32
#define DD   64
#define HIDN 2048      // H*D
#define NQKV 2176      // (H+2)*D
#define QK_SCALE 0.125f

typedef __attribute__((ext_vector_type(8))) short short8;
typedef __attribute__((ext_vector_type(4))) float f32x4;
typedef __attribute__((ext_vector_type(4))) unsigned short ushort4_t;

__device__ inline unsigned short f2bf(float f) {
  unsigned int u = __builtin_bit_cast(unsigned int, f);
  u += 0x7FFFu + ((u >> 16) & 1u);   // round-to-nearest-even
  return (unsigned short)(u >> 16);
}
__device__ inline float bf2f(unsigned short s) {
  unsigned int u = ((unsigned int)s) << 16;
  return __builtin_bit_cast(float, u);
}

// ---------------------------------------------------------------- f32 -> bf16
__global__ __launch_bounds__(256)
void cvt_kernel(const float* __restrict__ in, unsigned short* __restrict__ out, int n4) {
  int i = blockIdx.x * 256 + threadIdx.x;
  if (i >= n4) return;
  float4 v = ((const float4*)in)[i];
  ushort4_t u = { f2bf(v.x), f2bf(v.y), f2bf(v.z), f2bf(v.w) };
  *(ushort4_t*)(out + (long)i * 4) = u;
}

// ------------------------------------------------- C = A(MxK) * B(NxK)^T GEMM
// bf16 inputs (row-major, K inner), f32 accum. 128x128 tile, BK=32,
// 4 waves of 64x64, global_load_lds width-16 staging, 16x16x32 bf16 MFMA.
template<int OUT_BF16>
__global__ __launch_bounds__(256)
void gemm_bt(const unsigned short* __restrict__ A, const unsigned short* __restrict__ Bw,
             void* __restrict__ Cp, int M, int N, int K) {
  __shared__ unsigned short lA[128 * 32];
  __shared__ unsigned short lB[128 * 32];
  const int tid  = threadIdx.x;
  const int lane = tid & 63;
  const int wv   = tid >> 6;
  const int wr   = wv >> 1, wc = wv & 1;
  const int g    = lane >> 4, qq = lane & 15;
  const long bm0 = (long)blockIdx.y * 128;
  const long bn0 = (long)blockIdx.x * 128;
  const int srow  = tid >> 2;          // staging row 0..63
  const int skoff = (tid & 3) << 3;    // k offset (ushorts)

  f32x4 zero = {0.f, 0.f, 0.f, 0.f};
  f32x4 acc[4][4];
#pragma unroll
  for (int m = 0; m < 4; ++m)
#pragma unroll
    for (int n = 0; n < 4; ++n) acc[m][n] = zero;

  const unsigned short* aSrc = A  + (bm0 + srow) * K + skoff;
  const unsigned short* bSrc = Bw + (bn0 + srow) * K + skoff;

  for (int k0 = 0; k0 < K; k0 += 32) {
    __syncthreads();   // previous tile's compute done before overwrite
    __builtin_amdgcn_global_load_lds(
        (const __attribute__((address_space(1))) unsigned int*)(aSrc + k0),
        (__attribute__((address_space(3))) unsigned int*)(lA + wv * 512), 16, 0, 0);
    __builtin_amdgcn_global_load_lds(
        (const __attribute__((address_space(1))) unsigned int*)(aSrc + (long)64 * K + k0),
        (__attribute__((address_space(3))) unsigned int*)(lA + 2048 + wv * 512), 16, 0, 0);
    __builtin_amdgcn_global_load_lds(
        (const __attribute__((address_space(1))) unsigned int*)(bSrc + k0),
        (__attribute__((address_space(3))) unsigned int*)(lB + wv * 512), 16, 0, 0);
    __builtin_amdgcn_global_load_lds(
        (const __attribute__((address_space(1))) unsigned int*)(bSrc + (long)64 * K + k0),
        (__attribute__((address_space(3))) unsigned int*)(lB + 2048 + wv * 512), 16, 0, 0);
    __syncthreads();   // drains vmcnt -> staged data visible

    short8 af[4], bf[4];
#pragma unroll
    for (int m = 0; m < 4; ++m)
      af[m] = *(const short8*)&lA[(wr * 64 + m * 16 + qq) * 32 + g * 8];
#pragma unroll
    for (int n = 0; n < 4; ++n)
      bf[n] = *(const short8*)&lB[(wc * 64 + n * 16 + qq) * 32 + g * 8];
#pragma unroll
    for (int m = 0; m < 4; ++m)
#pragma unroll
      for (int n = 0; n < 4; ++n)
        acc[m][n] = __builtin_amdgcn_mfma_f32_16x16x32_bf16(af[m], bf[n], acc[m][n], 0, 0, 0);
  }

  // epilogue: C/D layout col=lane&15, row=(lane>>4)*4+reg
#pragma unroll
  for (int m = 0; m < 4; ++m) {
#pragma unroll
    for (int r = 0; r < 4; ++r) {
      long row = bm0 + wr * 64 + m * 16 + g * 4 + r;
#pragma unroll
      for (int n = 0; n < 4; ++n) {
        long col = bn0 + wc * 64 + n * 16 + qq;
        float v = acc[m][n][r];
        if (OUT_BF16) ((unsigned short*)Cp)[row * N + col] = f2bf(v);
        else          ((float*)Cp)[row * N + col] = v;
      }
    }
  }
}

// --------------------------------------------------------- RoPE + split + V^T
// qkv (T x 2176 bf16) -> q_out (T,H,D) scaled by QK_SCALE, k_out (T,D),
// v_out transposed (B, D, S). One thread per (t, head34, pair i<32).
__global__ __launch_bounds__(256)
void rope_kernel(const unsigned short* __restrict__ qkv, const float* __restrict__ cosb,
                 const float* __restrict__ sinb, unsigned short* __restrict__ q_out,
                 unsigned short* __restrict__ k_out, unsigned short* __restrict__ v_out) {
  int idx = blockIdx.x * 256 + threadIdx.x;
  if (idx >= TT * 34 * 32) return;
  int t   = idx / (34 * 32);
  int rem = idx - t * (34 * 32);
  int hh  = rem >> 5;
  int i   = rem & 31;
  const unsigned short* row = qkv + (long)t * NQKV;
  if (hh < 32) {                 // q heads (+fold 1/sqrt(D))
    float cv = cosb[t * 32 + i], sv = sinb[t * 32 + i];
    float x1 = bf2f(row[hh * 64 + i]);
    float x2 = bf2f(row[hh * 64 + 32 + i]);
    unsigned short* qr = q_out + ((long)t * 32 + hh) * 64;
    qr[i]      = f2bf((x1 * cv - x2 * sv) * QK_SCALE);
    qr[32 + i] = f2bf((x2 * cv + x1 * sv) * QK_SCALE);
  } else if (hh == 32) {         // k head
    float cv = cosb[t * 32 + i], sv = sinb[t * 32 + i];
    float x1 = bf2f(row[2048 + i]);
    float x2 = bf2f(row[2048 + 32 + i]);
    k_out[(long)t * 64 + i]      = f2bf(x1 * cv - x2 * sv);
    k_out[(long)t * 64 + 32 + i] = f2bf(x2 * cv + x1 * sv);
  } else {                       // v head -> transposed (B, D, S)
    int b = t >> 11, s = t & 2047;
    v_out[((long)(b * 64 + i)) * 2048 + s]      = row[2112 + i];
    v_out[((long)(b * 64 + 32 + i)) * 2048 + s] = row[2112 + 32 + i];
  }
}

// -------------------------------------------------------------- flash attention
// Wave-independent: each wave owns 16 q rows of one (b,h). Swapped QK^T
// (mfma(K,Q)) => scores^T [kv][q]: softmax state per q-column = lane&15.
// PV: A = P^T (redistributed via shfl), B = V^T rows (contiguous b128).
__global__ __launch_bounds__(256)
void attn_kernel(const unsigned short* __restrict__ qs, const unsigned short* __restrict__ kr,
                 const unsigned short* __restrict__ vt, unsigned short* __restrict__ ob) {
  const int lane = threadIdx.x & 63;
  const int wv   = threadIdx.x >> 6;
  const int g    = lane >> 4, c = lane & 15;
  const int h    = blockIdx.y, b = blockIdx.z;
  const int q0   = blockIdx.x * 64 + wv * 16;

  const unsigned short* qrow = qs + ((long)(b * SS + q0 + c) * HH + h) * 64;
  short8 qf0 = *(const short8*)(qrow + g * 8);
  short8 qf1 = *(const short8*)(qrow + 32 + g * 8);
  const unsigned short* kb = kr + (long)b * SS * 64;
  const unsigned short* vb = vt + (long)b * 64 * SS;

  f32x4 zero = {0.f, 0.f, 0.f, 0.f};
  f32x4 oc[4];
#pragma unroll
  for (int dt = 0; dt < 4; ++dt) oc[dt] = zero;
  float mst = -1e30f, lst = 0.f;

  const int nb = q0 / 64 + 1;
  for (int ib = 0; ib < nb; ++ib) {
    const int kv0 = ib * 64;
    f32x4 st[4];
#pragma unroll
    for (int t = 0; t < 4; ++t) {
      const unsigned short* krow = kb + (long)(kv0 + t * 16 + c) * 64;
      short8 k0f = *(const short8*)(krow + g * 8);
      short8 k1f = *(const short8*)(krow + 32 + g * 8);
      f32x4 z = zero;
      z     = __builtin_amdgcn_mfma_f32_16x16x32_bf16(k0f, qf0, z, 0, 0, 0);
      st[t] = __builtin_amdgcn_mfma_f32_16x16x32_bf16(k1f, qf1, st[t] = z, 0, 0, 0);
    }
    if (kv0 + 63 > q0) {           // causal mask on partial blocks: kv > q
#pragma unroll
      for (int t = 0; t < 4; ++t)
#pragma unroll
        for (int r = 0; r < 4; ++r)
          if (kv0 + t * 16 + g * 4 + r > q0 + c) st[t][r] = -1e30f;
    }
    // online softmax over kv (regs r, tiles t within lane; groups g via shfl)
    float pmax = -1e30f;
#pragma unroll
    for (int t = 0; t < 4; ++t)
#pragma unroll
      for (int r = 0; r < 4; ++r) pmax = fmaxf(pmax, st[t][r]);
    pmax = fmaxf(pmax, __shfl_xor(pmax, 16));
    pmax = fmaxf(pmax, __shfl_xor(pmax, 32));
    const float mnew = fmaxf(mst, pmax);
    const float scal = __expf(mst - mnew);
    float p[4][4];
    float psum = 0.f;
#pragma unroll
    for (int t = 0; t < 4; ++t)
#pragma unroll
      for (int r = 0; r < 4; ++r) {
        float e = __expf(st[t][r] - mnew);
        p[t][r] = e; psum += e;
      }
    psum += __shfl_xor(psum, 16);
    psum += __shfl_xor(psum, 32);
    lst = lst * scal + psum;
    mst = mnew;
    // rescale O accumulator (O rows are q_local = 4g+r; state lives at lane q)
#pragma unroll
    for (int r = 0; r < 4; ++r) {
      float sf = __shfl(scal, g * 4 + r);
#pragma unroll
      for (int dt = 0; dt < 4; ++dt) oc[dt][r] *= sf;
    }
    // PV: build P^T A-fragments (kv = ch*32 + 8g + j, q = c) then MFMA with V^T
#pragma unroll
    for (int ch = 0; ch < 2; ++ch) {
      short8 paf;
#pragma unroll
      for (int j = 0; j < 8; ++j) {
        int src = ((g & 1) * 2 + (j >> 2)) * 16 + c;   // lane holding that kv,q
        float va  = __shfl(p[2 * ch][j & 3], src);
        float vbv = __shfl(p[2 * ch + 1][j & 3], src);
        paf[j] = (short)f2bf((g >> 1) ? vbv : va);
      }
#pragma unroll
      for (int dt = 0; dt < 4; ++dt) {
        const unsigned short* vrow = vb + (long)(dt * 16 + c) * SS + kv0 + ch * 32 + g * 8;
        short8 vf = *(const short8*)vrow;
        oc[dt] = __builtin_amdgcn_mfma_f32_16x16x32_bf16(paf, vf, oc[dt], 0, 0, 0);
      }
    }
  }
  // finalize: divide by l and store (row q_local = 4g+r, col d = dt*16 + c)
#pragma unroll
  for (int r = 0; r < 4; ++r) {
    float lf  = __shfl(lst, g * 4 + r);
    float inv = 1.f / lf;
    long  row = (long)(b * SS + q0 + g * 4 + r);
#pragma unroll
    for (int dt = 0; dt < 4; ++dt)
      ob[(row * HH + h) * 64 + dt * 16 + c] = f2bf(oc[dt][r] * inv);
  }
}

// ------------------------------------------------------------------- launcher
extern "C" void kernel_launch(void* const* d_in, const int* in_sizes, int n_in,
                              void* d_out, int out_size, void* d_ws, size_t ws_size,
                              hipStream_t stream) {
  const float* hs   = (const float*)d_in[0];
  const float* cosb = (const float*)d_in[1];
  const float* sinb = (const float*)d_in[2];
  const float* wqkv = (const float*)d_in[3];
  const float* wd   = (const float*)d_in[4];

  char* ws = (char*)d_ws;
  // hs_bf region (16 MB) is reused as the attention-output bf16 buffer:
  // hidden is fully consumed by the QKV GEMM before attn writes it.
  unsigned short* hs_bf   = (unsigned short*)(ws);
  unsigned short* wqkv_bf = (unsigned short*)(ws + 16777216);
  unsigned short* wd_bf   = (unsigned short*)(ws + 25690112);
  unsigned short* qkv_bf  = (unsigned short*)(ws + 34078720);
  unsigned short* q_bf    = (unsigned short*)(ws + 51904512);
  unsigned short* k_bf    = (unsigned short*)(ws + 68681728);
  unsigned short* vt_bf   = (unsigned short*)(ws + 69206016);

  cvt_kernel<<<8192, 256, 0, stream>>>(hs,   hs_bf,   2097152);
  cvt_kernel<<<4352, 256, 0, stream>>>(wqkv, wqkv_bf, 1114112);
  cvt_kernel<<<4096, 256, 0, stream>>>(wd,   wd_bf,   1048576);

  gemm_bt<1><<<dim3(17, 32), 256, 0, stream>>>(hs_bf, wqkv_bf, qkv_bf, TT, NQKV, HIDN);

  rope_kernel<<<17408, 256, 0, stream>>>(qkv_bf, cosb, sinb, q_bf, k_bf, vt_bf);

  attn_kernel<<<dim3(SS / 64, HH, BB), 256, 0, stream>>>(q_bf, k_bf, vt_bf, hs_bf);

  gemm_bt<0><<<dim3(16, 32), 256, 0, stream>>>(hs_bf, wd_bf, d_out, TT, HIDN, HIDN);
}

// Round 2
// 355.825 us; speedup vs baseline: 1.6901x; 1.6901x over previous
//
#include <hip/hip_runtime.h>

// Problem constants
#define BB   2
#define SS   2048
#define TT   4096      // B*S
#define HH   32
#define DD   64
#define HIDN 2048      // H*D
#define NQKV 2176      // (H+2)*D
#define QK_SCALE 0.125f

typedef __attribute__((ext_vector_type(8))) short short8;
typedef __attribute__((ext_vector_type(4))) float f32x4;
typedef __attribute__((ext_vector_type(16))) float f32x16;
typedef __attribute__((ext_vector_type(4))) unsigned short ushort4_t;
typedef __attribute__((ext_vector_type(4))) unsigned int uint4_t;

__device__ inline unsigned short f2bf(float f) {
  unsigned int u = __builtin_bit_cast(unsigned int, f);
  u += 0x7FFFu + ((u >> 16) & 1u);   // round-to-nearest-even
  return (unsigned short)(u >> 16);
}
__device__ inline float bf2f(unsigned short s) {
  unsigned int u = ((unsigned int)s) << 16;
  return __builtin_bit_cast(float, u);
}
__device__ inline unsigned int pk2(float lo, float hi) {   // bf16x2 pack
  return ((unsigned int)f2bf(hi) << 16) | (unsigned int)f2bf(lo);
}

// ---------------------------------------------------------------- f32 -> bf16
__global__ __launch_bounds__(256)
void cvt_kernel(const float* __restrict__ in, unsigned short* __restrict__ out, int n4) {
  int i = blockIdx.x * 256 + threadIdx.x;
  if (i >= n4) return;
  float4 v = ((const float4*)in)[i];
  ushort4_t u = { f2bf(v.x), f2bf(v.y), f2bf(v.z), f2bf(v.w) };
  *(ushort4_t*)(out + (long)i * 4) = u;
}

// ------------------------------------------------- C = A(MxK) * B(NxK)^T GEMM
// bf16 inputs (row-major, K inner), f32 accum. 128x128 tile, BK=32,
// 4 waves of 64x64, global_load_lds width-16 staging, 16x16x32 bf16 MFMA.
template<int OUT_BF16>
__global__ __launch_bounds__(256)
void gemm_bt(const unsigned short* __restrict__ A, const unsigned short* __restrict__ Bw,
             void* __restrict__ Cp, int M, int N, int K) {
  __shared__ unsigned short lA[128 * 32];
  __shared__ unsigned short lB[128 * 32];
  const int tid  = threadIdx.x;
  const int lane = tid & 63;
  const int wv   = tid >> 6;
  const int wr   = wv >> 1, wc = wv & 1;
  const int g    = lane >> 4, qq = lane & 15;
  const long bm0 = (long)blockIdx.y * 128;
  const long bn0 = (long)blockIdx.x * 128;
  const int srow  = tid >> 2;          // staging row 0..63
  const int skoff = (tid & 3) << 3;    // k offset (ushorts)

  f32x4 zero = {0.f, 0.f, 0.f, 0.f};
  f32x4 acc[4][4];
#pragma unroll
  for (int m = 0; m < 4; ++m)
#pragma unroll
    for (int n = 0; n < 4; ++n) acc[m][n] = zero;

  const unsigned short* aSrc = A  + (bm0 + srow) * K + skoff;
  const unsigned short* bSrc = Bw + (bn0 + srow) * K + skoff;

  for (int k0 = 0; k0 < K; k0 += 32) {
    __syncthreads();   // previous tile's compute done before overwrite
    __builtin_amdgcn_global_load_lds(
        (const __attribute__((address_space(1))) unsigned int*)(aSrc + k0),
        (__attribute__((address_space(3))) unsigned int*)(lA + wv * 512), 16, 0, 0);
    __builtin_amdgcn_global_load_lds(
        (const __attribute__((address_space(1))) unsigned int*)(aSrc + (long)64 * K + k0),
        (__attribute__((address_space(3))) unsigned int*)(lA + 2048 + wv * 512), 16, 0, 0);
    __builtin_amdgcn_global_load_lds(
        (const __attribute__((address_space(1))) unsigned int*)(bSrc + k0),
        (__attribute__((address_space(3))) unsigned int*)(lB + wv * 512), 16, 0, 0);
    __builtin_amdgcn_global_load_lds(
        (const __attribute__((address_space(1))) unsigned int*)(bSrc + (long)64 * K + k0),
        (__attribute__((address_space(3))) unsigned int*)(lB + 2048 + wv * 512), 16, 0, 0);
    __syncthreads();   // drains vmcnt -> staged data visible

    short8 af[4], bf[4];
#pragma unroll
    for (int m = 0; m < 4; ++m)
      af[m] = *(const short8*)&lA[(wr * 64 + m * 16 + qq) * 32 + g * 8];
#pragma unroll
    for (int n = 0; n < 4; ++n)
      bf[n] = *(const short8*)&lB[(wc * 64 + n * 16 + qq) * 32 + g * 8];
#pragma unroll
    for (int m = 0; m < 4; ++m)
#pragma unroll
      for (int n = 0; n < 4; ++n)
        acc[m][n] = __builtin_amdgcn_mfma_f32_16x16x32_bf16(af[m], bf[n], acc[m][n], 0, 0, 0);
  }

  // epilogue: C/D layout col=lane&15, row=(lane>>4)*4+reg
#pragma unroll
  for (int m = 0; m < 4; ++m) {
#pragma unroll
    for (int r = 0; r < 4; ++r) {
      long row = bm0 + wr * 64 + m * 16 + g * 4 + r;
#pragma unroll
      for (int n = 0; n < 4; ++n) {
        long col = bn0 + wc * 64 + n * 16 + qq;
        float v = acc[m][n][r];
        if (OUT_BF16) ((unsigned short*)Cp)[row * N + col] = f2bf(v);
        else          ((float*)Cp)[row * N + col] = v;
      }
    }
  }
}

// --------------------------------------------------------- RoPE + split + V^T
// qkv (T x 2176 bf16) -> q_out (T,H,D) scaled by QK_SCALE, k_out (T,D),
// v_out transposed (B, D, S). One thread per (t, head34, pair i<32).
__global__ __launch_bounds__(256)
void rope_kernel(const unsigned short* __restrict__ qkv, const float* __restrict__ cosb,
                 const float* __restrict__ sinb, unsigned short* __restrict__ q_out,
                 unsigned short* __restrict__ k_out, unsigned short* __restrict__ v_out) {
  int idx = blockIdx.x * 256 + threadIdx.x;
  if (idx >= TT * 34 * 32) return;
  int t   = idx / (34 * 32);
  int rem = idx - t * (34 * 32);
  int hh  = rem >> 5;
  int i   = rem & 31;
  const unsigned short* row = qkv + (long)t * NQKV;
  if (hh < 32) {                 // q heads (+fold 1/sqrt(D))
    float cv = cosb[t * 32 + i], sv = sinb[t * 32 + i];
    float x1 = bf2f(row[hh * 64 + i]);
    float x2 = bf2f(row[hh * 64 + 32 + i]);
    unsigned short* qr = q_out + ((long)t * 32 + hh) * 64;
    qr[i]      = f2bf((x1 * cv - x2 * sv) * QK_SCALE);
    qr[32 + i] = f2bf((x2 * cv + x1 * sv) * QK_SCALE);
  } else if (hh == 32) {         // k head
    float cv = cosb[t * 32 + i], sv = sinb[t * 32 + i];
    float x1 = bf2f(row[2048 + i]);
    float x2 = bf2f(row[2048 + 32 + i]);
    k_out[(long)t * 64 + i]      = f2bf(x1 * cv - x2 * sv);
    k_out[(long)t * 64 + 32 + i] = f2bf(x2 * cv + x1 * sv);
  } else {                       // v head -> transposed (B, D, S)
    int b = t >> 11, s = t & 2047;
    v_out[((long)(b * 64 + i)) * 2048 + s]      = row[2112 + i];
    v_out[((long)(b * 64 + 32 + i)) * 2048 + s] = row[2112 + 32 + i];
  }
}

// -------------------------------------------------------------- flash attention
// One wave = 32 q-rows of one head (QBLK=32), KVBLK=32, 32x32x16 MFMA.
// Swapped QK^T: S^T = mfma(A=K[kv][d], B=Q^T[d][q]) => lane owns q = lane&31;
// softmax max/sum are in-register over 16 C-regs + one shfl_xor(32).
// O^T[d][q] = mfma(A=V^T[d][kv], B=P^T[kv][q]); P^T B-frags built in-register
// from the S^T C-regs via bf16x2 packs + 4 shfl_xor(32) per k-step pair.
// C/D layout (verified): col = lane&31, row = (reg&3) + 8*(reg>>2) + 4*(lane>>5).
__global__ __launch_bounds__(256)
void attn_kernel(const unsigned short* __restrict__ qs, const unsigned short* __restrict__ kr,
                 const unsigned short* __restrict__ vt, unsigned short* __restrict__ ob) {
  const int lane = threadIdx.x & 63;
  const int wv   = threadIdx.x >> 6;
  const int half = lane >> 5;          // 0/1 (k-chunk / row-offset selector)
  const int qc   = lane & 31;          // q column owned by this lane
  const int h    = blockIdx.y * 4 + wv;
  const int b    = blockIdx.z;
  const int qt   = (SS / 32 - 1) - blockIdx.x;   // biggest triangles first
  const int q0   = qt * 32;

  const unsigned short* kb = kr + (long)b * SS * 64;
  const unsigned short* vb = vt + (long)b * 64 * SS;

  // Q B-fragments (k = d): lane holds q-row q0+qc, d = dstep*16 + half*8 + j
  short8 qf[4];
  const unsigned short* qrow = qs + ((long)(b * SS + q0 + qc) * HH + h) * 64;
#pragma unroll
  for (int dstep = 0; dstep < 4; ++dstep)
    qf[dstep] = *(const short8*)(qrow + dstep * 16 + half * 8);

  f32x16 o0, o1;                       // O^T accum: d = [0,32) and [32,64)
#pragma unroll
  for (int r = 0; r < 16; ++r) { o0[r] = 0.f; o1[r] = 0.f; }
  float mst = -1e30f, lst = 0.f;

  for (int kv0 = 0; kv0 <= q0; kv0 += 32) {
    // ---- QK^T: S^T[kv][q], kv rows = C rows, q = lane col
    f32x16 st;
#pragma unroll
    for (int r = 0; r < 16; ++r) st[r] = 0.f;
#pragma unroll
    for (int dstep = 0; dstep < 4; ++dstep) {
      short8 kf = *(const short8*)(kb + (long)(kv0 + qc) * 64 + dstep * 16 + half * 8);
      st = __builtin_amdgcn_mfma_f32_32x32x16_bf16(kf, qf[dstep], st, 0, 0, 0);
    }
    if (kv0 == q0) {                   // causal mask, diagonal block only
#pragma unroll
      for (int r = 0; r < 16; ++r) {
        int rkv = (r & 3) + 8 * (r >> 2) + 4 * half;
        if (rkv > qc) st[r] = -1e30f;
      }
    }
    // ---- online softmax (state per q = lane-local)
    float pmax = st[0];
#pragma unroll
    for (int r = 1; r < 16; ++r) pmax = fmaxf(pmax, st[r]);
    pmax = fmaxf(pmax, __shfl_xor(pmax, 32));
    const float mnew = fmaxf(mst, pmax);
    const float scal = __expf(mst - mnew);
    float p[16];
    float psum = 0.f;
#pragma unroll
    for (int r = 0; r < 16; ++r) { p[r] = __expf(st[r] - mnew); psum += p[r]; }
    psum += __shfl_xor(psum, 32);
    lst = lst * scal + psum;
    mst = mnew;
#pragma unroll
    for (int r = 0; r < 16; ++r) { o0[r] *= scal; o1[r] *= scal; }

    // ---- P^T -> B-fragments (2 k-steps of 16 kv each)
    // rows at this lane: p[r] = kv (r&3) + 8*(r>>2) + 4*half
    unsigned int pk01 = pk2(p[0],  p[1]),  pk23 = pk2(p[2],  p[3]);
    unsigned int pk45 = pk2(p[4],  p[5]),  pk67 = pk2(p[6],  p[7]);
    unsigned int pk89 = pk2(p[8],  p[9]),  pkAB = pk2(p[10], p[11]);
    unsigned int pkCD = pk2(p[12], p[13]), pkEF = pk2(p[14], p[15]);
    unsigned int x01 = __shfl_xor((int)pk01, 32), x23 = __shfl_xor((int)pk23, 32);
    unsigned int x45 = __shfl_xor((int)pk45, 32), x67 = __shfl_xor((int)pk67, 32);
    unsigned int x89 = __shfl_xor((int)pk89, 32), xAB = __shfl_xor((int)pkAB, 32);
    unsigned int xCD = __shfl_xor((int)pkCD, 32), xEF = __shfl_xor((int)pkEF, 32);
    uint4_t w0u = { half ? x45 : pk01, half ? x67 : pk23,
                    half ? pk45 : x01, half ? pk67 : x23 };   // kv 0..15
    uint4_t w1u = { half ? xCD : pk89, half ? xEF : pkAB,
                    half ? pkCD : x89, half ? pkEF : xAB };   // kv 16..31
    short8 pb0 = __builtin_bit_cast(short8, w0u);
    short8 pb1 = __builtin_bit_cast(short8, w1u);

    // ---- PV: O^T[d][q] += V^T[d][kv] * P^T[kv][q]
    const unsigned short* v0 = vb + (long)(qc) * SS + kv0 + half * 8;
    const unsigned short* v1 = vb + (long)(32 + qc) * SS + kv0 + half * 8;
    short8 vf00 = *(const short8*)(v0);
    short8 vf01 = *(const short8*)(v0 + 16);
    short8 vf10 = *(const short8*)(v1);
    short8 vf11 = *(const short8*)(v1 + 16);
    o0 = __builtin_amdgcn_mfma_f32_32x32x16_bf16(vf00, pb0, o0, 0, 0, 0);
    o0 = __builtin_amdgcn_mfma_f32_32x32x16_bf16(vf01, pb1, o0, 0, 0, 0);
    o1 = __builtin_amdgcn_mfma_f32_32x32x16_bf16(vf10, pb0, o1, 0, 0, 0);
    o1 = __builtin_amdgcn_mfma_f32_32x32x16_bf16(vf11, pb1, o1, 0, 0, 0);
  }

  // ---- finalize: O[q][d] = O^T[d][q] / l;  q = qc (lane-local l state)
  const float inv = 1.f / lst;
  unsigned short* orow = ob + ((long)(b * SS + q0 + qc) * HH + h) * 64;
#pragma unroll
  for (int r = 0; r < 16; ++r) {
    int d0 = (r & 3) + 8 * (r >> 2) + 4 * half;
    orow[d0]      = f2bf(o0[r] * inv);
    orow[32 + d0] = f2bf(o1[r] * inv);
  }
}

// ------------------------------------------------------------------- launcher
extern "C" void kernel_launch(void* const* d_in, const int* in_sizes, int n_in,
                              void* d_out, int out_size, void* d_ws, size_t ws_size,
                              hipStream_t stream) {
  const float* hs   = (const float*)d_in[0];
  const float* cosb = (const float*)d_in[1];
  const float* sinb = (const float*)d_in[2];
  const float* wqkv = (const float*)d_in[3];
  const float* wd   = (const float*)d_in[4];

  char* ws = (char*)d_ws;
  // hs_bf region (16 MB) is reused as the attention-output bf16 buffer:
  // hidden is fully consumed by the QKV GEMM before attn writes it.
  unsigned short* hs_bf   = (unsigned short*)(ws);
  unsigned short* wqkv_bf = (unsigned short*)(ws + 16777216);
  unsigned short* wd_bf   = (unsigned short*)(ws + 25690112);
  unsigned short* qkv_bf  = (unsigned short*)(ws + 34078720);
  unsigned short* q_bf    = (unsigned short*)(ws + 51904512);
  unsigned short* k_bf    = (unsigned short*)(ws + 68681728);
  unsigned short* vt_bf   = (unsigned short*)(ws + 69206016);

  cvt_kernel<<<8192, 256, 0, stream>>>(hs,   hs_bf,   2097152);
  cvt_kernel<<<4352, 256, 0, stream>>>(wqkv, wqkv_bf, 1114112);
  cvt_kernel<<<4096, 256, 0, stream>>>(wd,   wd_bf,   1048576);

  gemm_bt<1><<<dim3(17, 32), 256, 0, stream>>>(hs_bf, wqkv_bf, qkv_bf, TT, NQKV, HIDN);

  rope_kernel<<<17408, 256, 0, stream>>>(qkv_bf, cosb, sinb, q_bf, k_bf, vt_bf);

  attn_kernel<<<dim3(SS / 32, 8, BB), 256, 0, stream>>>(q_bf, k_bf, vt_bf, hs_bf);

  gemm_bt<0><<<dim3(16, 32), 256, 0, stream>>>(hs_bf, wd_bf, d_out, TT, HIDN, HIDN);
}

// Round 4
// 287.262 us; speedup vs baseline: 2.0935x; 1.2387x over previous
//
#include <hip/hip_runtime.h>

// Problem constants
#define BB   2
#define SS   2048
#define TT   4096      // B*S
#define HH   32
#define DD   64
#define HIDN 2048      // H*D
#define NQKV 2176      // (H+2)*D
#define QK_SCALE 0.125f

#define AS1 __attribute__((address_space(1)))
#define AS3 __attribute__((address_space(3)))

typedef __attribute__((ext_vector_type(8))) short short8;
typedef __attribute__((ext_vector_type(4))) float f32x4;
typedef __attribute__((ext_vector_type(16))) float f32x16;
typedef __attribute__((ext_vector_type(4))) unsigned short ushort4_t;
typedef __attribute__((ext_vector_type(4))) unsigned int uint4_t;

__device__ inline unsigned short f2bf(float f) {
  unsigned int u = __builtin_bit_cast(unsigned int, f);
  u += 0x7FFFu + ((u >> 16) & 1u);   // round-to-nearest-even
  return (unsigned short)(u >> 16);
}
__device__ inline float bf2f(unsigned short s) {
  unsigned int u = ((unsigned int)s) << 16;
  return __builtin_bit_cast(float, u);
}
__device__ inline unsigned int pk2(float lo, float hi) {   // bf16x2 pack
  return ((unsigned int)f2bf(hi) << 16) | (unsigned int)f2bf(lo);
}

// ---------------------------------------------------------------- f32 -> bf16
__global__ __launch_bounds__(256)
void cvt_kernel(const float* __restrict__ in, unsigned short* __restrict__ out, int n4) {
  int i = blockIdx.x * 256 + threadIdx.x;
  if (i >= n4) return;
  float4 v = ((const float4*)in)[i];
  ushort4_t u = { f2bf(v.x), f2bf(v.y), f2bf(v.z), f2bf(v.w) };
  *(ushort4_t*)(out + (long)i * 4) = u;
}

// ------------------------------------------------- C = A(MxK) * B(NxK)^T GEMM
template<int OUT_BF16>
__global__ __launch_bounds__(256)
void gemm_bt(const unsigned short* __restrict__ A, const unsigned short* __restrict__ Bw,
             void* __restrict__ Cp, int M, int N, int K) {
  __shared__ unsigned short lA[128 * 32];
  __shared__ unsigned short lB[128 * 32];
  const int tid  = threadIdx.x;
  const int lane = tid & 63;
  const int wv   = tid >> 6;
  const int wr   = wv >> 1, wc = wv & 1;
  const int g    = lane >> 4, qq = lane & 15;
  const long bm0 = (long)blockIdx.y * 128;
  const long bn0 = (long)blockIdx.x * 128;
  const int srow  = tid >> 2;          // staging row 0..63
  const int skoff = (tid & 3) << 3;    // k offset (ushorts)

  f32x4 zero = {0.f, 0.f, 0.f, 0.f};
  f32x4 acc[4][4];
#pragma unroll
  for (int m = 0; m < 4; ++m)
#pragma unroll
    for (int n = 0; n < 4; ++n) acc[m][n] = zero;

  const unsigned short* aSrc = A  + (bm0 + srow) * K + skoff;
  const unsigned short* bSrc = Bw + (bn0 + srow) * K + skoff;

  for (int k0 = 0; k0 < K; k0 += 32) {
    __syncthreads();   // previous tile's compute done before overwrite
    __builtin_amdgcn_global_load_lds(
        (const AS1 unsigned int*)(aSrc + k0),
        (AS3 unsigned int*)(lA + wv * 512), 16, 0, 0);
    __builtin_amdgcn_global_load_lds(
        (const AS1 unsigned int*)(aSrc + (long)64 * K + k0),
        (AS3 unsigned int*)(lA + 2048 + wv * 512), 16, 0, 0);
    __builtin_amdgcn_global_load_lds(
        (const AS1 unsigned int*)(bSrc + k0),
        (AS3 unsigned int*)(lB + wv * 512), 16, 0, 0);
    __builtin_amdgcn_global_load_lds(
        (const AS1 unsigned int*)(bSrc + (long)64 * K + k0),
        (AS3 unsigned int*)(lB + 2048 + wv * 512), 16, 0, 0);
    __syncthreads();   // drains vmcnt -> staged data visible

    short8 af[4], bf[4];
#pragma unroll
    for (int m = 0; m < 4; ++m)
      af[m] = *(const short8*)&lA[(wr * 64 + m * 16 + qq) * 32 + g * 8];
#pragma unroll
    for (int n = 0; n < 4; ++n)
      bf[n] = *(const short8*)&lB[(wc * 64 + n * 16 + qq) * 32 + g * 8];
#pragma unroll
    for (int m = 0; m < 4; ++m)
#pragma unroll
      for (int n = 0; n < 4; ++n)
        acc[m][n] = __builtin_amdgcn_mfma_f32_16x16x32_bf16(af[m], bf[n], acc[m][n], 0, 0, 0);
  }

  // epilogue: C/D layout col=lane&15, row=(lane>>4)*4+reg
#pragma unroll
  for (int m = 0; m < 4; ++m) {
#pragma unroll
    for (int r = 0; r < 4; ++r) {
      long row = bm0 + wr * 64 + m * 16 + g * 4 + r;
#pragma unroll
      for (int n = 0; n < 4; ++n) {
        long col = bn0 + wc * 64 + n * 16 + qq;
        float v = acc[m][n][r];
        if (OUT_BF16) ((unsigned short*)Cp)[row * N + col] = f2bf(v);
        else          ((float*)Cp)[row * N + col] = v;
      }
    }
  }
}

// --------------------------------------------------------- RoPE + split + V^T
// qkv (T x 2176 bf16) -> q_out (T,H,D) scaled by QK_SCALE, k_out (T,D),
// v_out TILED-transposed: [B][S/64 tiles][64 d][64 s-in-tile] so each attn
// V^T-tile is one contiguous 8 KB block (coalesced global_load_lds staging).
__global__ __launch_bounds__(256)
void rope_kernel(const unsigned short* __restrict__ qkv, const float* __restrict__ cosb,
                 const float* __restrict__ sinb, unsigned short* __restrict__ q_out,
                 unsigned short* __restrict__ k_out, unsigned short* __restrict__ v_out) {
  int idx = blockIdx.x * 256 + threadIdx.x;
  if (idx >= TT * 34 * 32) return;
  int t   = idx / (34 * 32);
  int rem = idx - t * (34 * 32);
  int hh  = rem >> 5;
  int i   = rem & 31;
  const unsigned short* row = qkv + (long)t * NQKV;
  if (hh < 32) {                 // q heads (+fold 1/sqrt(D))
    float cv = cosb[t * 32 + i], sv = sinb[t * 32 + i];
    float x1 = bf2f(row[hh * 64 + i]);
    float x2 = bf2f(row[hh * 64 + 32 + i]);
    unsigned short* qr = q_out + ((long)t * 32 + hh) * 64;
    qr[i]      = f2bf((x1 * cv - x2 * sv) * QK_SCALE);
    qr[32 + i] = f2bf((x2 * cv + x1 * sv) * QK_SCALE);
  } else if (hh == 32) {         // k head
    float cv = cosb[t * 32 + i], sv = sinb[t * 32 + i];
    float x1 = bf2f(row[2048 + i]);
    float x2 = bf2f(row[2048 + 32 + i]);
    k_out[(long)t * 64 + i]      = f2bf(x1 * cv - x2 * sv);
    k_out[(long)t * 64 + 32 + i] = f2bf(x2 * cv + x1 * sv);
  } else {                       // v head -> tiled transpose [B][S/64][64 d][64 s]
    int bb = t >> 11, s = t & 2047;
    int tile = s >> 6, c = s & 63;
    long base = ((long)bb * 32 + tile) * 64;   // row units (rows of 64 ushorts)
    v_out[(base + i) * 64 + c]      = row[2112 + i];
    v_out[(base + 32 + i) * 64 + c] = row[2112 + 32 + i];
  }
}

// -------------------------------------------------------------- flash attention
// Block = 4 waves = 4 heads at the same (b, q-tile); MQA => waves share K/V.
// KVBLK=64: K-tile [64 kv][64 d] (8 KB) and V^T-tile [64 d][64 kv] (8 KB)
// staged in LDS per block, SINGLE buffer, m97-proven two-barrier structure
// (barrier -> stage -> vmcnt(0)+barrier -> compute; no loads in flight across
// barriers -- the round-3 overlapped variant raced under graph replay).
// Both tiles are [64 rows][128 B] with XOR swizzle sigma(row)=(row&7)<<4
// applied both-sides (linear LDS dest + pre-swizzled global source + swizzled
// read offsets). Per wave: swapped QK^T (S^T = mfma(K,Q), lane owns q=lane&31,
// lane-local softmax), P^T built in-register, O^T = V^T * P^T.
__global__ __launch_bounds__(256)
void attn_kernel(const unsigned short* __restrict__ qs, const unsigned short* __restrict__ kr,
                 const unsigned short* __restrict__ vt, unsigned short* __restrict__ ob) {
  __shared__ unsigned char lsm[16384];   // [K 8KB | V 8KB]
  const int tid  = threadIdx.x;
  const int lane = tid & 63;
  const int wv   = tid >> 6;
  const int half = lane >> 5;
  const int qc   = lane & 31;
  const int h    = blockIdx.y * 4 + wv;
  const int b    = blockIdx.z;
  const int qt   = (SS / 32 - 1) - blockIdx.x;   // biggest triangles first
  const int q0   = qt * 32;
  const int nb   = (q0 >> 6) + 1;                // 64-kv blocks

  const unsigned short* kb  = kr + (long)b * SS * 64;
  const unsigned short* vtb = vt + (long)b * (SS / 64) * 64 * 64;

  // ---- staging coords: both tiles [64 rows][128 B]; thread loads rows
  // krow and krow+32 at inverse-swizzled byte col (swizzle same for both).
  const int krow  = tid >> 3;                                // 0..31
  const int kcolb = ((tid & 7) << 4) ^ ((krow & 7) << 4);    // bytes in row

  // ---- swizzled LDS read offsets (lane-constant). Rows qc / 32+qc.
  const int rswz = (qc & 7) << 4;
  int koff[4], voff[4];
#pragma unroll
  for (int i = 0; i < 4; ++i) {
    koff[i] = qc * 128 + ((i * 32 + half * 16) ^ rswz);          // K: i = dstep
    voff[i] = 8192 + qc * 128 + ((i * 32 + half * 16) ^ rswz);   // V: i = kstep
  }

  // ---- Q B-fragments: lane holds q-row q0+qc, k(=d) = dstep*16 + half*8 + j
  short8 qf[4];
  const unsigned short* qrow = qs + ((long)(b * SS + q0 + qc) * HH + h) * 64;
#pragma unroll
  for (int dstep = 0; dstep < 4; ++dstep)
    qf[dstep] = *(const short8*)(qrow + dstep * 16 + half * 8);

  f32x16 o0, o1;                       // O^T accum: d in [0,32) and [32,64)
#pragma unroll
  for (int r = 0; r < 16; ++r) { o0[r] = 0.f; o1[r] = 0.f; }
  float mst = -1e30f, lst = 0.f;

  for (int ib = 0; ib < nb; ++ib) {
    const int kv0 = ib * 64;
    __syncthreads();                   // all waves done reading previous tile
    {
      const unsigned short* kS = kb + ((long)(kv0 + krow)) * 64 + (kcolb >> 1);
      __builtin_amdgcn_global_load_lds((const AS1 unsigned int*)kS,
          (AS3 unsigned int*)(lsm + wv * 1024), 16, 0, 0);
      __builtin_amdgcn_global_load_lds((const AS1 unsigned int*)(kS + 32 * 64),
          (AS3 unsigned int*)(lsm + 4096 + wv * 1024), 16, 0, 0);
      const unsigned short* vS = vtb + (long)ib * 4096 + krow * 64 + (kcolb >> 1);
      __builtin_amdgcn_global_load_lds((const AS1 unsigned int*)vS,
          (AS3 unsigned int*)(lsm + 8192 + wv * 1024), 16, 0, 0);
      __builtin_amdgcn_global_load_lds((const AS1 unsigned int*)(vS + 32 * 64),
          (AS3 unsigned int*)(lsm + 12288 + wv * 1024), 16, 0, 0);
    }
    __syncthreads();                   // drains vmcnt -> staged data visible

    // ---- QK^T: S^T[kv][q], kv 0..31 -> st0, 32..63 -> st1
    f32x16 st0, st1;
#pragma unroll
    for (int r = 0; r < 16; ++r) { st0[r] = 0.f; st1[r] = 0.f; }
#pragma unroll
    for (int dstep = 0; dstep < 4; ++dstep) {
      short8 kfA = *(const short8*)(lsm + koff[dstep]);
      short8 kfB = *(const short8*)(lsm + koff[dstep] + 4096);
      st0 = __builtin_amdgcn_mfma_f32_32x32x16_bf16(kfA, qf[dstep], st0, 0, 0, 0);
      st1 = __builtin_amdgcn_mfma_f32_32x32x16_bf16(kfB, qf[dstep], st1, 0, 0, 0);
    }
    if (ib == nb - 1) {                // causal mask (only last block partial)
#pragma unroll
      for (int r = 0; r < 16; ++r) {
        int rkv = (r & 3) + 8 * (r >> 2) + 4 * half;
        if (kv0 + rkv      > q0 + qc) st0[r] = -1e30f;
        if (kv0 + 32 + rkv > q0 + qc) st1[r] = -1e30f;
      }
    }
    // ---- online softmax (state per q = lane-local)
    float pmax = st0[0];
#pragma unroll
    for (int r = 1; r < 16; ++r) pmax = fmaxf(pmax, st0[r]);
#pragma unroll
    for (int r = 0; r < 16; ++r) pmax = fmaxf(pmax, st1[r]);
    pmax = fmaxf(pmax, __shfl_xor(pmax, 32));
    const float mnew = fmaxf(mst, pmax);
    const float scal = __expf(mst - mnew);
    float p0[16], p1[16];
    float psum = 0.f;
#pragma unroll
    for (int r = 0; r < 16; ++r) { p0[r] = __expf(st0[r] - mnew); psum += p0[r]; }
#pragma unroll
    for (int r = 0; r < 16; ++r) { p1[r] = __expf(st1[r] - mnew); psum += p1[r]; }
    psum += __shfl_xor(psum, 32);
    lst = lst * scal + psum;
    mst = mnew;
#pragma unroll
    for (int r = 0; r < 16; ++r) { o0[r] *= scal; o1[r] *= scal; }

    // ---- P^T -> B-fragments (kv rows at this lane: (r&3)+8*(r>>2)+4*half [+32])
    short8 pb[4];
#pragma unroll
    for (int hseg = 0; hseg < 2; ++hseg) {
      const float* pp = hseg ? p1 : p0;
      unsigned int a0 = pk2(pp[0],  pp[1]),  a1 = pk2(pp[2],  pp[3]);
      unsigned int a2 = pk2(pp[4],  pp[5]),  a3 = pk2(pp[6],  pp[7]);
      unsigned int a4 = pk2(pp[8],  pp[9]),  a5 = pk2(pp[10], pp[11]);
      unsigned int a6 = pk2(pp[12], pp[13]), a7 = pk2(pp[14], pp[15]);
      unsigned int x0 = __shfl_xor((int)a0, 32), x1 = __shfl_xor((int)a1, 32);
      unsigned int x2 = __shfl_xor((int)a2, 32), x3 = __shfl_xor((int)a3, 32);
      unsigned int x4 = __shfl_xor((int)a4, 32), x5 = __shfl_xor((int)a5, 32);
      unsigned int x6 = __shfl_xor((int)a6, 32), x7 = __shfl_xor((int)a7, 32);
      uint4_t w0 = { half ? x2 : a0, half ? x3 : a1,
                     half ? a2 : x0, half ? a3 : x1 };   // kv seg+[0,16)
      uint4_t w1 = { half ? x6 : a4, half ? x7 : a5,
                     half ? a6 : x4, half ? a7 : x5 };   // kv seg+[16,32)
      pb[hseg * 2]     = __builtin_bit_cast(short8, w0);
      pb[hseg * 2 + 1] = __builtin_bit_cast(short8, w1);
    }

    // ---- PV: O^T[d][q] += V^T[d][kv] * P^T[kv][q]  (4 ksteps of 16 kv)
#pragma unroll
    for (int ks = 0; ks < 4; ++ks) {
      short8 vfA = *(const short8*)(lsm + voff[ks]);
      short8 vfB = *(const short8*)(lsm + voff[ks] + 4096);
      o0 = __builtin_amdgcn_mfma_f32_32x32x16_bf16(vfA, pb[ks], o0, 0, 0, 0);
      o1 = __builtin_amdgcn_mfma_f32_32x32x16_bf16(vfB, pb[ks], o1, 0, 0, 0);
    }
  }

  // ---- finalize: O[q][d] = O^T[d][q] / l;  q = qc (lane-local l state)
  const float inv = 1.f / lst;
  unsigned short* orow = ob + ((long)(b * SS + q0 + qc) * HH + h) * 64;
#pragma unroll
  for (int r = 0; r < 16; ++r) {
    int d0 = (r & 3) + 8 * (r >> 2) + 4 * half;
    orow[d0]      = f2bf(o0[r] * inv);
    orow[32 + d0] = f2bf(o1[r] * inv);
  }
}

// ------------------------------------------------------------------- launcher
extern "C" void kernel_launch(void* const* d_in, const int* in_sizes, int n_in,
                              void* d_out, int out_size, void* d_ws, size_t ws_size,
                              hipStream_t stream) {
  const float* hs   = (const float*)d_in[0];
  const float* cosb = (const float*)d_in[1];
  const float* sinb = (const float*)d_in[2];
  const float* wqkv = (const float*)d_in[3];
  const float* wd   = (const float*)d_in[4];

  char* ws = (char*)d_ws;
  // hs_bf region (16 MB) is reused as the attention-output bf16 buffer:
  // hidden is fully consumed by the QKV GEMM before attn writes it.
  unsigned short* hs_bf   = (unsigned short*)(ws);
  unsigned short* wqkv_bf = (unsigned short*)(ws + 16777216);
  unsigned short* wd_bf   = (unsigned short*)(ws + 25690112);
  unsigned short* qkv_bf  = (unsigned short*)(ws + 34078720);
  unsigned short* q_bf    = (unsigned short*)(ws + 51904512);
  unsigned short* k_bf    = (unsigned short*)(ws + 68681728);
  unsigned short* vt_bf   = (unsigned short*)(ws + 69206016);

  cvt_kernel<<<8192, 256, 0, stream>>>(hs,   hs_bf,   2097152);
  cvt_kernel<<<4352, 256, 0, stream>>>(wqkv, wqkv_bf, 1114112);
  cvt_kernel<<<4096, 256, 0, stream>>>(wd,   wd_bf,   1048576);

  gemm_bt<1><<<dim3(17, 32), 256, 0, stream>>>(hs_bf, wqkv_bf, qkv_bf, TT, NQKV, HIDN);

  rope_kernel<<<17408, 256, 0, stream>>>(qkv_bf, cosb, sinb, q_bf, k_bf, vt_bf);

  attn_kernel<<<dim3(SS / 32, 8, BB), 256, 0, stream>>>(q_bf, k_bf, vt_bf, hs_bf);

  gemm_bt<0><<<dim3(16, 32), 256, 0, stream>>>(hs_bf, wd_bf, d_out, TT, HIDN, HIDN);
}

// Round 6
// 251.511 us; speedup vs baseline: 2.3911x; 1.1421x over previous
//
#include <hip/hip_runtime.h>

// Problem constants
#define BB   2
#define SS   2048
#define TT   4096      // B*S
#define HH   32
#define DD   64
#define HIDN 2048      // H*D
#define NQKV 2176      // (H+2)*D
#define QK_SCALE 0.125f

#define AS1 __attribute__((address_space(1)))
#define AS3 __attribute__((address_space(3)))

typedef __attribute__((ext_vector_type(8))) short short8;
typedef __attribute__((ext_vector_type(4))) float f32x4;
typedef __attribute__((ext_vector_type(16))) float f32x16;
typedef __attribute__((ext_vector_type(4))) unsigned short ushort4_t;
typedef __attribute__((ext_vector_type(4))) unsigned int uint4_t;

__device__ inline unsigned short f2bf(float f) {
  unsigned int u = __builtin_bit_cast(unsigned int, f);
  u += 0x7FFFu + ((u >> 16) & 1u);   // round-to-nearest-even
  return (unsigned short)(u >> 16);
}
__device__ inline float bf2f(unsigned short s) {
  unsigned int u = ((unsigned int)s) << 16;
  return __builtin_bit_cast(float, u);
}
__device__ inline unsigned int pk2(float lo, float hi) {   // bf16x2 pack
  return ((unsigned int)f2bf(hi) << 16) | (unsigned int)f2bf(lo);
}

// ---------------------------------------------------------------- f32 -> bf16
__global__ __launch_bounds__(256)
void cvt_kernel(const float* __restrict__ in, unsigned short* __restrict__ out, int n4) {
  int i = blockIdx.x * 256 + threadIdx.x;
  if (i >= n4) return;
  float4 v = ((const float4*)in)[i];
  ushort4_t u = { f2bf(v.x), f2bf(v.y), f2bf(v.z), f2bf(v.w) };
  *(ushort4_t*)(out + (long)i * 4) = u;
}

// ------------------------------------------------- C = A(MxK) * B(NxK)^T GEMM
template<int OUT_BF16>
__global__ __launch_bounds__(256)
void gemm_bt(const unsigned short* __restrict__ A, const unsigned short* __restrict__ Bw,
             void* __restrict__ Cp, int M, int N, int K) {
  __shared__ unsigned short lA[128 * 32];
  __shared__ unsigned short lB[128 * 32];
  const int tid  = threadIdx.x;
  const int lane = tid & 63;
  const int wv   = tid >> 6;
  const int wr   = wv >> 1, wc = wv & 1;
  const int g    = lane >> 4, qq = lane & 15;
  const long bm0 = (long)blockIdx.y * 128;
  const long bn0 = (long)blockIdx.x * 128;
  const int srow  = tid >> 2;          // staging row 0..63
  const int skoff = (tid & 3) << 3;    // k offset (ushorts)

  f32x4 zero = {0.f, 0.f, 0.f, 0.f};
  f32x4 acc[4][4];
#pragma unroll
  for (int m = 0; m < 4; ++m)
#pragma unroll
    for (int n = 0; n < 4; ++n) acc[m][n] = zero;

  const unsigned short* aSrc = A  + (bm0 + srow) * K + skoff;
  const unsigned short* bSrc = Bw + (bn0 + srow) * K + skoff;

  for (int k0 = 0; k0 < K; k0 += 32) {
    __syncthreads();   // previous tile's compute done before overwrite
    __builtin_amdgcn_global_load_lds(
        (const AS1 unsigned int*)(aSrc + k0),
        (AS3 unsigned int*)(lA + wv * 512), 16, 0, 0);
    __builtin_amdgcn_global_load_lds(
        (const AS1 unsigned int*)(aSrc + (long)64 * K + k0),
        (AS3 unsigned int*)(lA + 2048 + wv * 512), 16, 0, 0);
    __builtin_amdgcn_global_load_lds(
        (const AS1 unsigned int*)(bSrc + k0),
        (AS3 unsigned int*)(lB + wv * 512), 16, 0, 0);
    __builtin_amdgcn_global_load_lds(
        (const AS1 unsigned int*)(bSrc + (long)64 * K + k0),
        (AS3 unsigned int*)(lB + 2048 + wv * 512), 16, 0, 0);
    __syncthreads();   // drains vmcnt -> staged data visible

    short8 af[4], bf[4];
#pragma unroll
    for (int m = 0; m < 4; ++m)
      af[m] = *(const short8*)&lA[(wr * 64 + m * 16 + qq) * 32 + g * 8];
#pragma unroll
    for (int n = 0; n < 4; ++n)
      bf[n] = *(const short8*)&lB[(wc * 64 + n * 16 + qq) * 32 + g * 8];
#pragma unroll
    for (int m = 0; m < 4; ++m)
#pragma unroll
      for (int n = 0; n < 4; ++n)
        acc[m][n] = __builtin_amdgcn_mfma_f32_16x16x32_bf16(af[m], bf[n], acc[m][n], 0, 0, 0);
  }

  // epilogue: C/D layout col=lane&15, row=(lane>>4)*4+reg
#pragma unroll
  for (int m = 0; m < 4; ++m) {
#pragma unroll
    for (int r = 0; r < 4; ++r) {
      long row = bm0 + wr * 64 + m * 16 + g * 4 + r;
#pragma unroll
      for (int n = 0; n < 4; ++n) {
        long col = bn0 + wc * 64 + n * 16 + qq;
        float v = acc[m][n][r];
        if (OUT_BF16) ((unsigned short*)Cp)[row * N + col] = f2bf(v);
        else          ((float*)Cp)[row * N + col] = v;
      }
    }
  }
}

// --------------------------------------------------------- RoPE + split + V^T
// qkv (T x 2176 bf16) -> q_out (T,H,D) scaled by QK_SCALE, k_out (T,D),
// v_out TILED-transposed: [B][S/64 tiles][64 d][64 s-in-tile] so each attn
// V^T-tile is one contiguous 8 KB block (coalesced staging).
__global__ __launch_bounds__(256)
void rope_kernel(const unsigned short* __restrict__ qkv, const float* __restrict__ cosb,
                 const float* __restrict__ sinb, unsigned short* __restrict__ q_out,
                 unsigned short* __restrict__ k_out, unsigned short* __restrict__ v_out) {
  int idx = blockIdx.x * 256 + threadIdx.x;
  if (idx >= TT * 34 * 32) return;
  int t   = idx / (34 * 32);
  int rem = idx - t * (34 * 32);
  int hh  = rem >> 5;
  int i   = rem & 31;
  const unsigned short* row = qkv + (long)t * NQKV;
  if (hh < 32) {                 // q heads (+fold 1/sqrt(D))
    float cv = cosb[t * 32 + i], sv = sinb[t * 32 + i];
    float x1 = bf2f(row[hh * 64 + i]);
    float x2 = bf2f(row[hh * 64 + 32 + i]);
    unsigned short* qr = q_out + ((long)t * 32 + hh) * 64;
    qr[i]      = f2bf((x1 * cv - x2 * sv) * QK_SCALE);
    qr[32 + i] = f2bf((x2 * cv + x1 * sv) * QK_SCALE);
  } else if (hh == 32) {         // k head
    float cv = cosb[t * 32 + i], sv = sinb[t * 32 + i];
    float x1 = bf2f(row[2048 + i]);
    float x2 = bf2f(row[2048 + 32 + i]);
    k_out[(long)t * 64 + i]      = f2bf(x1 * cv - x2 * sv);
    k_out[(long)t * 64 + 32 + i] = f2bf(x2 * cv + x1 * sv);
  } else {                       // v head -> tiled transpose [B][S/64][64 d][64 s]
    int bb = t >> 11, s = t & 2047;
    int tile = s >> 6, c = s & 63;
    long base = ((long)bb * 32 + tile) * 64;   // row units (rows of 64 ushorts)
    v_out[(base + i) * 64 + c]      = row[2112 + i];
    v_out[(base + 32 + i) * 64 + c] = row[2112 + 32 + i];
  }
}

// -------------------------------------------------------------- flash attention
// Block = 8 waves = 8 heads at the same (b, q-tile); MQA => waves share K/V.
// KVBLK=64. PROVEN two-barrier skeleton (round 4, post-timing validated):
//   per iter: barrier -> issue global_load_lds (K 8KB + V 8KB, single buffer)
//             -> barrier (drains vmcnt) -> compute.
// No memory ops in flight across barriers (rounds 3/5 overlapped variants
// raced under graph replay -- sync skeleton is frozen to this form).
// Tiles are [64 rows][128 B], XOR swizzle sigma(row)=(row&7)<<4 applied
// both-sides (linear LDS dest + pre-swizzled global source + swizzled read
// offsets). Per wave: swapped QK^T (S^T = mfma(K,Q), lane owns q=lane&31,
// lane-local softmax, defer-max THR=8), P^T built in-register (bf16x2 packs
// + shfl_xor(32)), O^T = V^T * P^T.
__global__ __launch_bounds__(512, 4)
void attn_kernel(const unsigned short* __restrict__ qs, const unsigned short* __restrict__ kr,
                 const unsigned short* __restrict__ vt, unsigned short* __restrict__ ob) {
  __shared__ unsigned char lsm[16384];   // [K 8KB | V 8KB]
  const int tid  = threadIdx.x;
  const int lane = tid & 63;
  const int wv   = tid >> 6;          // 0..7
  const int half = lane >> 5;
  const int qc   = lane & 31;
  const int h    = blockIdx.y * 8 + wv;
  const int b    = blockIdx.z;
  const int qt   = (SS / 32 - 1) - blockIdx.x;   // biggest triangles first
  const int q0   = qt * 32;
  const int nb   = (q0 >> 6) + 1;                // 64-kv blocks

  const unsigned short* kb  = kr + (long)b * SS * 64;
  const unsigned short* vtb = vt + (long)b * (SS / 64) * 64 * 64;

  // ---- staging: thread owns row (tid>>3) 16B at linear col (tid&7)*16 for
  // both K and V tiles; global source col is inverse-swizzled.
  const int srow  = tid >> 3;                                // 0..63
  const int scolb = ((tid & 7) << 4) ^ ((srow & 7) << 4);    // swizzled src col

  // ---- swizzled LDS read offsets (lane-constant). Rows qc / 32+qc.
  const int rswz = (qc & 7) << 4;
  int koff[4], voff[4];
#pragma unroll
  for (int i = 0; i < 4; ++i) {
    koff[i] = qc * 128 + ((i * 32 + half * 16) ^ rswz);          // K: i = dstep
    voff[i] = 8192 + qc * 128 + ((i * 32 + half * 16) ^ rswz);   // V: i = kstep
  }

  // ---- Q B-fragments: lane holds q-row q0+qc, k(=d) = dstep*16 + half*8 + j
  short8 qf[4];
  const unsigned short* qrow = qs + ((long)(b * SS + q0 + qc) * HH + h) * 64;
#pragma unroll
  for (int dstep = 0; dstep < 4; ++dstep)
    qf[dstep] = *(const short8*)(qrow + dstep * 16 + half * 8);

  f32x16 o0, o1;                       // O^T accum: d in [0,32) and [32,64)
#pragma unroll
  for (int r = 0; r < 16; ++r) { o0[r] = 0.f; o1[r] = 0.f; }
  float mst = -1e30f, lst = 0.f;

  for (int ib = 0; ib < nb; ++ib) {
    const int kv0 = ib * 64;
    __syncthreads();                   // all waves done reading previous tile
    {
      const unsigned short* kS = kb + ((long)(kv0 + srow)) * 64 + (scolb >> 1);
      __builtin_amdgcn_global_load_lds((const AS1 unsigned int*)kS,
          (AS3 unsigned int*)(lsm + wv * 1024), 16, 0, 0);
      const unsigned short* vS = vtb + (long)ib * 4096 + srow * 64 + (scolb >> 1);
      __builtin_amdgcn_global_load_lds((const AS1 unsigned int*)vS,
          (AS3 unsigned int*)(lsm + 8192 + wv * 1024), 16, 0, 0);
    }
    __syncthreads();                   // drains vmcnt -> staged data visible

    // ---- QK^T: S^T[kv][q], kv 0..31 -> st0, 32..63 -> st1
    f32x16 st0, st1;
#pragma unroll
    for (int r = 0; r < 16; ++r) { st0[r] = 0.f; st1[r] = 0.f; }
#pragma unroll
    for (int dstep = 0; dstep < 4; ++dstep) {
      short8 kfA = *(const short8*)(lsm + koff[dstep]);
      short8 kfB = *(const short8*)(lsm + koff[dstep] + 4096);
      st0 = __builtin_amdgcn_mfma_f32_32x32x16_bf16(kfA, qf[dstep], st0, 0, 0, 0);
      st1 = __builtin_amdgcn_mfma_f32_32x32x16_bf16(kfB, qf[dstep], st1, 0, 0, 0);
    }
    if (ib == nb - 1) {                // causal mask (only last block partial)
#pragma unroll
      for (int r = 0; r < 16; ++r) {
        int rkv = (r & 3) + 8 * (r >> 2) + 4 * half;
        if (kv0 + rkv      > q0 + qc) st0[r] = -1e30f;
        if (kv0 + 32 + rkv > q0 + qc) st1[r] = -1e30f;
      }
    }
    // ---- online softmax (state per q = lane-local), defer-max THR=8
    float pmax = st0[0];
#pragma unroll
    for (int r = 1; r < 16; ++r) pmax = fmaxf(pmax, st0[r]);
#pragma unroll
    for (int r = 0; r < 16; ++r) pmax = fmaxf(pmax, st1[r]);
    pmax = fmaxf(pmax, __shfl_xor(pmax, 32));
    if (!__all(pmax - mst <= 8.f)) {
      const float mnew = fmaxf(mst, pmax);
      const float scal = __expf(mst - mnew);
      lst *= scal;
#pragma unroll
      for (int r = 0; r < 16; ++r) { o0[r] *= scal; o1[r] *= scal; }
      mst = mnew;
    }
    float psum = 0.f;
#pragma unroll
    for (int r = 0; r < 16; ++r) { st0[r] = __expf(st0[r] - mst); psum += st0[r]; }
#pragma unroll
    for (int r = 0; r < 16; ++r) { st1[r] = __expf(st1[r] - mst); psum += st1[r]; }
    psum += __shfl_xor(psum, 32);
    lst += psum;

    // ---- P^T -> B-fragments (kv rows at this lane: (r&3)+8*(r>>2)+4*half [+32])
    short8 pb[4];
#pragma unroll
    for (int hseg = 0; hseg < 2; ++hseg) {
      const f32x16& pp = hseg ? st1 : st0;
      unsigned int a0 = pk2(pp[0],  pp[1]),  a1 = pk2(pp[2],  pp[3]);
      unsigned int a2 = pk2(pp[4],  pp[5]),  a3 = pk2(pp[6],  pp[7]);
      unsigned int a4 = pk2(pp[8],  pp[9]),  a5 = pk2(pp[10], pp[11]);
      unsigned int a6 = pk2(pp[12], pp[13]), a7 = pk2(pp[14], pp[15]);
      unsigned int x0 = __shfl_xor((int)a0, 32), x1 = __shfl_xor((int)a1, 32);
      unsigned int x2 = __shfl_xor((int)a2, 32), x3 = __shfl_xor((int)a3, 32);
      unsigned int x4 = __shfl_xor((int)a4, 32), x5 = __shfl_xor((int)a5, 32);
      unsigned int x6 = __shfl_xor((int)a6, 32), x7 = __shfl_xor((int)a7, 32);
      uint4_t w0 = { half ? x2 : a0, half ? x3 : a1,
                     half ? a2 : x0, half ? a3 : x1 };   // kv seg+[0,16)
      uint4_t w1 = { half ? x6 : a4, half ? x7 : a5,
                     half ? a6 : x4, half ? a7 : x5 };   // kv seg+[16,32)
      pb[hseg * 2]     = __builtin_bit_cast(short8, w0);
      pb[hseg * 2 + 1] = __builtin_bit_cast(short8, w1);
    }

    // ---- PV: O^T[d][q] += V^T[d][kv] * P^T[kv][q]  (4 ksteps of 16 kv)
#pragma unroll
    for (int ks = 0; ks < 4; ++ks) {
      short8 vfA = *(const short8*)(lsm + voff[ks]);
      short8 vfB = *(const short8*)(lsm + voff[ks] + 4096);
      o0 = __builtin_amdgcn_mfma_f32_32x32x16_bf16(vfA, pb[ks], o0, 0, 0, 0);
      o1 = __builtin_amdgcn_mfma_f32_32x32x16_bf16(vfB, pb[ks], o1, 0, 0, 0);
    }
  }

  // ---- finalize: O[q][d] = O^T[d][q] / l;  q = qc (lane-local l state)
  const float inv = 1.f / lst;
  unsigned short* orow = ob + ((long)(b * SS + q0 + qc) * HH + h) * 64;
#pragma unroll
  for (int r = 0; r < 16; ++r) {
    int d0 = (r & 3) + 8 * (r >> 2) + 4 * half;
    orow[d0]      = f2bf(o0[r] * inv);
    orow[32 + d0] = f2bf(o1[r] * inv);
  }
}

// ------------------------------------------------------------------- launcher
extern "C" void kernel_launch(void* const* d_in, const int* in_sizes, int n_in,
                              void* d_out, int out_size, void* d_ws, size_t ws_size,
                              hipStream_t stream) {
  const float* hs   = (const float*)d_in[0];
  const float* cosb = (const float*)d_in[1];
  const float* sinb = (const float*)d_in[2];
  const float* wqkv = (const float*)d_in[3];
  const float* wd   = (const float*)d_in[4];

  char* ws = (char*)d_ws;
  // hs_bf region (16 MB) is reused as the attention-output bf16 buffer:
  // hidden is fully consumed by the QKV GEMM before attn writes it.
  unsigned short* hs_bf   = (unsigned short*)(ws);
  unsigned short* wqkv_bf = (unsigned short*)(ws + 16777216);
  unsigned short* wd_bf   = (unsigned short*)(ws + 25690112);
  unsigned short* qkv_bf  = (unsigned short*)(ws + 34078720);
  unsigned short* q_bf    = (unsigned short*)(ws + 51904512);
  unsigned short* k_bf    = (unsigned short*)(ws + 68681728);
  unsigned short* vt_bf   = (unsigned short*)(ws + 69206016);

  cvt_kernel<<<8192, 256, 0, stream>>>(hs,   hs_bf,   2097152);
  cvt_kernel<<<4352, 256, 0, stream>>>(wqkv, wqkv_bf, 1114112);
  cvt_kernel<<<4096, 256, 0, stream>>>(wd,   wd_bf,   1048576);

  gemm_bt<1><<<dim3(17, 32), 256, 0, stream>>>(hs_bf, wqkv_bf, qkv_bf, TT, NQKV, HIDN);

  rope_kernel<<<17408, 256, 0, stream>>>(qkv_bf, cosb, sinb, q_bf, k_bf, vt_bf);

  attn_kernel<<<dim3(SS / 32, 4, BB), 512, 0, stream>>>(q_bf, k_bf, vt_bf, hs_bf);

  gemm_bt<0><<<dim3(16, 32), 256, 0, stream>>>(hs_bf, wd_bf, d_out, TT, HIDN, HIDN);
}

// Round 7
// 247.315 us; speedup vs baseline: 2.4316x; 1.0170x over previous
//
#include <hip/hip_runtime.h>

// Problem constants
#define BB   2
#define SS   2048
#define TT   4096      // B*S
#define HH   32
#define DD   64
#define HIDN 2048      // H*D
#define NQKV 2176      // (H+2)*D
#define QK_SCALE 0.125f

#define AS1 __attribute__((address_space(1)))
#define AS3 __attribute__((address_space(3)))

typedef __attribute__((ext_vector_type(8))) short short8;
typedef __attribute__((ext_vector_type(4))) float f32x4;
typedef __attribute__((ext_vector_type(16))) float f32x16;
typedef __attribute__((ext_vector_type(4))) unsigned short ushort4_t;
typedef __attribute__((ext_vector_type(4))) unsigned int uint4_t;

__device__ inline unsigned short f2bf(float f) {
  unsigned int u = __builtin_bit_cast(unsigned int, f);
  u += 0x7FFFu + ((u >> 16) & 1u);   // round-to-nearest-even
  return (unsigned short)(u >> 16);
}
__device__ inline float bf2f(unsigned short s) {
  unsigned int u = ((unsigned int)s) << 16;
  return __builtin_bit_cast(float, u);
}
__device__ inline unsigned int pk2(float lo, float hi) {   // bf16x2 pack
  return ((unsigned int)f2bf(hi) << 16) | (unsigned int)f2bf(lo);
}

// ---------------------------------------------------------------- f32 -> bf16
__global__ __launch_bounds__(256)
void cvt_kernel(const float* __restrict__ in, unsigned short* __restrict__ out, int n4) {
  int i = blockIdx.x * 256 + threadIdx.x;
  if (i >= n4) return;
  float4 v = ((const float4*)in)[i];
  ushort4_t u = { f2bf(v.x), f2bf(v.y), f2bf(v.z), f2bf(v.w) };
  *(ushort4_t*)(out + (long)i * 4) = u;
}

// ------------------------------------------------- C = A(MxK) * B(NxK)^T GEMM
template<int OUT_BF16>
__global__ __launch_bounds__(256)
void gemm_bt(const unsigned short* __restrict__ A, const unsigned short* __restrict__ Bw,
             void* __restrict__ Cp, int M, int N, int K) {
  __shared__ unsigned short lA[128 * 32];
  __shared__ unsigned short lB[128 * 32];
  const int tid  = threadIdx.x;
  const int lane = tid & 63;
  const int wv   = tid >> 6;
  const int wr   = wv >> 1, wc = wv & 1;
  const int g    = lane >> 4, qq = lane & 15;
  const long bm0 = (long)blockIdx.y * 128;
  const long bn0 = (long)blockIdx.x * 128;
  const int srow  = tid >> 2;          // staging row 0..63
  const int skoff = (tid & 3) << 3;    // k offset (ushorts)

  f32x4 zero = {0.f, 0.f, 0.f, 0.f};
  f32x4 acc[4][4];
#pragma unroll
  for (int m = 0; m < 4; ++m)
#pragma unroll
    for (int n = 0; n < 4; ++n) acc[m][n] = zero;

  const unsigned short* aSrc = A  + (bm0 + srow) * K + skoff;
  const unsigned short* bSrc = Bw + (bn0 + srow) * K + skoff;

  for (int k0 = 0; k0 < K; k0 += 32) {
    __syncthreads();   // previous tile's compute done before overwrite
    __builtin_amdgcn_global_load_lds(
        (const AS1 unsigned int*)(aSrc + k0),
        (AS3 unsigned int*)(lA + wv * 512), 16, 0, 0);
    __builtin_amdgcn_global_load_lds(
        (const AS1 unsigned int*)(aSrc + (long)64 * K + k0),
        (AS3 unsigned int*)(lA + 2048 + wv * 512), 16, 0, 0);
    __builtin_amdgcn_global_load_lds(
        (const AS1 unsigned int*)(bSrc + k0),
        (AS3 unsigned int*)(lB + wv * 512), 16, 0, 0);
    __builtin_amdgcn_global_load_lds(
        (const AS1 unsigned int*)(bSrc + (long)64 * K + k0),
        (AS3 unsigned int*)(lB + 2048 + wv * 512), 16, 0, 0);
    __syncthreads();   // drains vmcnt -> staged data visible

    short8 af[4], bf[4];
#pragma unroll
    for (int m = 0; m < 4; ++m)
      af[m] = *(const short8*)&lA[(wr * 64 + m * 16 + qq) * 32 + g * 8];
#pragma unroll
    for (int n = 0; n < 4; ++n)
      bf[n] = *(const short8*)&lB[(wc * 64 + n * 16 + qq) * 32 + g * 8];
#pragma unroll
    for (int m = 0; m < 4; ++m)
#pragma unroll
      for (int n = 0; n < 4; ++n)
        acc[m][n] = __builtin_amdgcn_mfma_f32_16x16x32_bf16(af[m], bf[n], acc[m][n], 0, 0, 0);
  }

  // epilogue: C/D layout col=lane&15, row=(lane>>4)*4+reg
#pragma unroll
  for (int m = 0; m < 4; ++m) {
#pragma unroll
    for (int r = 0; r < 4; ++r) {
      long row = bm0 + wr * 64 + m * 16 + g * 4 + r;
#pragma unroll
      for (int n = 0; n < 4; ++n) {
        long col = bn0 + wc * 64 + n * 16 + qq;
        float v = acc[m][n][r];
        if (OUT_BF16) ((unsigned short*)Cp)[row * N + col] = f2bf(v);
        else          ((float*)Cp)[row * N + col] = v;
      }
    }
  }
}

// --------------------------------------------------------- RoPE + split + V^T
// Vectorized (short8): one thread per (t, head34, octet-of-8). q heads get
// RoPE + QK_SCALE; k head RoPE; v head scattered into tiled-transposed
// [B][S/64 tiles][64 d][64 s] (8 KB contiguous tiles for attn staging).
__global__ __launch_bounds__(256)
void rope_kernel(const unsigned short* __restrict__ qkv, const float* __restrict__ cosb,
                 const float* __restrict__ sinb, unsigned short* __restrict__ q_out,
                 unsigned short* __restrict__ k_out, unsigned short* __restrict__ v_out) {
  int idx = blockIdx.x * 256 + threadIdx.x;
  if (idx >= TT * 136) return;           // 34 heads * 4 octets
  int t   = idx / 136;
  int rem = idx - t * 136;
  int hh  = rem >> 2;
  int i0  = (rem & 3) * 8;
  const unsigned short* row = qkv + (long)t * NQKV;

  if (hh < 33) {                         // rope path (q heads + k head)
    const unsigned short* src = row + (hh < 32 ? hh * 64 : 2048);
    short8 a = *(const short8*)(src + i0);
    short8 b = *(const short8*)(src + 32 + i0);
    float cv[8], sv[8];
    *(float4*)(cv)     = *(const float4*)(cosb + t * 32 + i0);
    *(float4*)(cv + 4) = *(const float4*)(cosb + t * 32 + i0 + 4);
    *(float4*)(sv)     = *(const float4*)(sinb + t * 32 + i0);
    *(float4*)(sv + 4) = *(const float4*)(sinb + t * 32 + i0 + 4);
    const float sc = (hh < 32) ? QK_SCALE : 1.f;
    short8 ra, rb;
#pragma unroll
    for (int j = 0; j < 8; ++j) {
      float x1 = bf2f((unsigned short)a[j]);
      float x2 = bf2f((unsigned short)b[j]);
      ra[j] = (short)f2bf((x1 * cv[j] - x2 * sv[j]) * sc);
      rb[j] = (short)f2bf((x2 * cv[j] + x1 * sv[j]) * sc);
    }
    unsigned short* dst = (hh < 32) ? q_out + ((long)t * 32 + hh) * 64
                                    : k_out + (long)t * 64;
    *(short8*)(dst + i0)      = ra;
    *(short8*)(dst + 32 + i0) = rb;
  } else {                               // v head -> tiled transpose scatter
    const unsigned short* src = row + 2112;
    short8 a = *(const short8*)(src + i0);
    short8 b = *(const short8*)(src + 32 + i0);
    int bb = t >> 11, s = t & 2047;
    int tile = s >> 6, c = s & 63;
    long base = ((long)bb * 32 + tile) * 64;   // row units (rows of 64 ushorts)
#pragma unroll
    for (int j = 0; j < 8; ++j) {
      v_out[(base + i0 + j) * 64 + c]      = (unsigned short)a[j];
      v_out[(base + 32 + i0 + j) * 64 + c] = (unsigned short)b[j];
    }
  }
}

// -------------------------------------------------------------- flash attention
// Block = 8 waves = 8 heads at the same (b, q-tile); MQA => waves share K/V.
// KVBLK=128 staged per barrier pair (K [128 kv][64 d] 16KB + two 8KB V^T
// tiles = 32KB LDS), then TWO 64-kv compute phases -- halves barrier/drain
// count vs round 6 at identical register pressure.
// PROVEN two-barrier skeleton (rounds 4/6, post-timing validated):
//   per iter: barrier -> issue global_load_lds -> barrier (drains) -> compute.
// No memory ops in flight across barriers (rounds 3/5 overlapped variants
// raced under graph replay -- sync skeleton frozen).
// Tiles are [rows][128 B] with XOR swizzle sigma(row)=(row&7)<<4 both-sides.
// Per wave: swapped QK^T (S^T = mfma(K,Q), lane owns q=lane&31, lane-local
// softmax, defer-max THR=8), P^T in-register (bf16x2 packs + shfl_xor(32)),
// O^T = V^T * P^T. s_setprio(1) around MFMA clusters (T5).
__global__ __launch_bounds__(512, 2)
void attn_kernel(const unsigned short* __restrict__ qs, const unsigned short* __restrict__ kr,
                 const unsigned short* __restrict__ vt, unsigned short* __restrict__ ob) {
  __shared__ unsigned char lsm[32768];   // K rows 0-63 | K rows 64-127 | V0 | V1 (8KB each)
  const int tid  = threadIdx.x;
  const int lane = tid & 63;
  const int wv   = tid >> 6;          // 0..7
  const int half = lane >> 5;
  const int qc   = lane & 31;
  const int h    = blockIdx.y * 8 + wv;
  const int b    = blockIdx.z;
  const int qt   = (SS / 32 - 1) - blockIdx.x;   // biggest triangles first
  const int q0   = qt * 32;
  const int nb   = (q0 >> 7) + 1;                // 128-kv blocks

  const unsigned short* kb  = kr + (long)b * SS * 64;
  const unsigned short* vtb = vt + (long)b * (SS / 64) * 64 * 64;

  // ---- staging: thread owns row (tid>>3) 16B at linear col (tid&7)*16;
  // global source col inverse-swizzled (ushort units).
  const int srow = tid >> 3;                                       // 0..63
  const int scol = ((((tid & 7) << 4) ^ ((srow & 7) << 4)) >> 1);  // ushorts

  // ---- swizzled LDS read offsets within a [64 rows][128B] subtile.
  const int rswz = (qc & 7) << 4;
  int roff[4];
#pragma unroll
  for (int i = 0; i < 4; ++i)
    roff[i] = qc * 128 + ((i * 32 + half * 16) ^ rswz);

  // ---- Q B-fragments: lane holds q-row q0+qc, k(=d) = dstep*16 + half*8 + j
  short8 qf[4];
  const unsigned short* qrow = qs + ((long)(b * SS + q0 + qc) * HH + h) * 64;
#pragma unroll
  for (int dstep = 0; dstep < 4; ++dstep)
    qf[dstep] = *(const short8*)(qrow + dstep * 16 + half * 8);

  f32x16 o0, o1;                       // O^T accum: d in [0,32) and [32,64)
#pragma unroll
  for (int r = 0; r < 16; ++r) { o0[r] = 0.f; o1[r] = 0.f; }
  float mst = -1e30f, lst = 0.f;

  for (int ib = 0; ib < nb; ++ib) {
    const int kv0   = ib * 128;
    const int lastt = (ib == nb - 1);
    __syncthreads();                   // all waves done reading previous tile
    {
      const unsigned short* kS = kb + ((long)(kv0 + srow)) * 64 + scol;
      __builtin_amdgcn_global_load_lds((const AS1 unsigned int*)kS,
          (AS3 unsigned int*)(lsm + wv * 1024), 16, 0, 0);
      __builtin_amdgcn_global_load_lds((const AS1 unsigned int*)(kS + 64 * 64),
          (AS3 unsigned int*)(lsm + 8192 + wv * 1024), 16, 0, 0);
      const unsigned short* vS = vtb + (long)(2 * ib) * 4096 + srow * 64 + scol;
      __builtin_amdgcn_global_load_lds((const AS1 unsigned int*)vS,
          (AS3 unsigned int*)(lsm + 16384 + wv * 1024), 16, 0, 0);
      __builtin_amdgcn_global_load_lds((const AS1 unsigned int*)(vS + 4096),
          (AS3 unsigned int*)(lsm + 24576 + wv * 1024), 16, 0, 0);
    }
    __syncthreads();                   // drains vmcnt -> staged data visible

    for (int ph = 0; ph < 2; ++ph) {
      if (ph && lastt && (q0 & 127) < 64) break;   // phase B fully masked
      const unsigned char* Kb = lsm + ph * 8192;
      const unsigned char* Vb = lsm + 16384 + ph * 8192;
      const int kvb = kv0 + ph * 64;

      // ---- QK^T: S^T[kv][q], kv kvb+[0,32) -> st0, kvb+[32,64) -> st1
      f32x16 st0, st1;
#pragma unroll
      for (int r = 0; r < 16; ++r) { st0[r] = 0.f; st1[r] = 0.f; }
      __builtin_amdgcn_s_setprio(1);
#pragma unroll
      for (int dstep = 0; dstep < 4; ++dstep) {
        short8 kfA = *(const short8*)(Kb + roff[dstep]);
        short8 kfB = *(const short8*)(Kb + roff[dstep] + 4096);
        st0 = __builtin_amdgcn_mfma_f32_32x32x16_bf16(kfA, qf[dstep], st0, 0, 0, 0);
        st1 = __builtin_amdgcn_mfma_f32_32x32x16_bf16(kfB, qf[dstep], st1, 0, 0, 0);
      }
      __builtin_amdgcn_s_setprio(0);
      if (lastt) {                     // causal mask (only last tile partial)
#pragma unroll
        for (int r = 0; r < 16; ++r) {
          int rkv = (r & 3) + 8 * (r >> 2) + 4 * half;
          if (kvb + rkv      > q0 + qc) st0[r] = -1e30f;
          if (kvb + 32 + rkv > q0 + qc) st1[r] = -1e30f;
        }
      }
      // ---- online softmax (state per q = lane-local), defer-max THR=8
      float pmax = st0[0];
#pragma unroll
      for (int r = 1; r < 16; ++r) pmax = fmaxf(pmax, st0[r]);
#pragma unroll
      for (int r = 0; r < 16; ++r) pmax = fmaxf(pmax, st1[r]);
      pmax = fmaxf(pmax, __shfl_xor(pmax, 32));
      if (!__all(pmax - mst <= 8.f)) {
        const float mnew = fmaxf(mst, pmax);
        const float scal = __expf(mst - mnew);
        lst *= scal;
#pragma unroll
        for (int r = 0; r < 16; ++r) { o0[r] *= scal; o1[r] *= scal; }
        mst = mnew;
      }
      float psum = 0.f;
#pragma unroll
      for (int r = 0; r < 16; ++r) { st0[r] = __expf(st0[r] - mst); psum += st0[r]; }
#pragma unroll
      for (int r = 0; r < 16; ++r) { st1[r] = __expf(st1[r] - mst); psum += st1[r]; }
      psum += __shfl_xor(psum, 32);
      lst += psum;

      // ---- P^T -> B-fragments (kv rows at this lane: (r&3)+8*(r>>2)+4*half [+32])
      short8 pb[4];
#pragma unroll
      for (int hseg = 0; hseg < 2; ++hseg) {
        const f32x16& pp = hseg ? st1 : st0;
        unsigned int a0 = pk2(pp[0],  pp[1]),  a1 = pk2(pp[2],  pp[3]);
        unsigned int a2 = pk2(pp[4],  pp[5]),  a3 = pk2(pp[6],  pp[7]);
        unsigned int a4 = pk2(pp[8],  pp[9]),  a5 = pk2(pp[10], pp[11]);
        unsigned int a6 = pk2(pp[12], pp[13]), a7 = pk2(pp[14], pp[15]);
        unsigned int x0 = __shfl_xor((int)a0, 32), x1 = __shfl_xor((int)a1, 32);
        unsigned int x2 = __shfl_xor((int)a2, 32), x3 = __shfl_xor((int)a3, 32);
        unsigned int x4 = __shfl_xor((int)a4, 32), x5 = __shfl_xor((int)a5, 32);
        unsigned int x6 = __shfl_xor((int)a6, 32), x7 = __shfl_xor((int)a7, 32);
        uint4_t w0 = { half ? x2 : a0, half ? x3 : a1,
                       half ? a2 : x0, half ? a3 : x1 };   // kv seg+[0,16)
        uint4_t w1 = { half ? x6 : a4, half ? x7 : a5,
                       half ? a6 : x4, half ? a7 : x5 };   // kv seg+[16,32)
        pb[hseg * 2]     = __builtin_bit_cast(short8, w0);
        pb[hseg * 2 + 1] = __builtin_bit_cast(short8, w1);
      }

      // ---- PV: O^T[d][q] += V^T[d][kv] * P^T[kv][q]  (4 ksteps of 16 kv)
      __builtin_amdgcn_s_setprio(1);
#pragma unroll
      for (int ks = 0; ks < 4; ++ks) {
        short8 vfA = *(const short8*)(Vb + roff[ks]);
        short8 vfB = *(const short8*)(Vb + roff[ks] + 4096);
        o0 = __builtin_amdgcn_mfma_f32_32x32x16_bf16(vfA, pb[ks], o0, 0, 0, 0);
        o1 = __builtin_amdgcn_mfma_f32_32x32x16_bf16(vfB, pb[ks], o1, 0, 0, 0);
      }
      __builtin_amdgcn_s_setprio(0);
    }
  }

  // ---- finalize: O[q][d] = O^T[d][q] / l;  q = qc (lane-local l state)
  const float inv = 1.f / lst;
  unsigned short* orow = ob + ((long)(b * SS + q0 + qc) * HH + h) * 64;
#pragma unroll
  for (int r = 0; r < 16; ++r) {
    int d0 = (r & 3) + 8 * (r >> 2) + 4 * half;
    orow[d0]      = f2bf(o0[r] * inv);
    orow[32 + d0] = f2bf(o1[r] * inv);
  }
}

// ------------------------------------------------------------------- launcher
extern "C" void kernel_launch(void* const* d_in, const int* in_sizes, int n_in,
                              void* d_out, int out_size, void* d_ws, size_t ws_size,
                              hipStream_t stream) {
  const float* hs   = (const float*)d_in[0];
  const float* cosb = (const float*)d_in[1];
  const float* sinb = (const float*)d_in[2];
  const float* wqkv = (const float*)d_in[3];
  const float* wd   = (const float*)d_in[4];

  char* ws = (char*)d_ws;
  // hs_bf region (16 MB) is reused as the attention-output bf16 buffer:
  // hidden is fully consumed by the QKV GEMM before attn writes it.
  unsigned short* hs_bf   = (unsigned short*)(ws);
  unsigned short* wqkv_bf = (unsigned short*)(ws + 16777216);
  unsigned short* wd_bf   = (unsigned short*)(ws + 25690112);
  unsigned short* qkv_bf  = (unsigned short*)(ws + 34078720);
  unsigned short* q_bf    = (unsigned short*)(ws + 51904512);
  unsigned short* k_bf    = (unsigned short*)(ws + 68681728);
  unsigned short* vt_bf   = (unsigned short*)(ws + 69206016);

  cvt_kernel<<<8192, 256, 0, stream>>>(hs,   hs_bf,   2097152);
  cvt_kernel<<<4352, 256, 0, stream>>>(wqkv, wqkv_bf, 1114112);
  cvt_kernel<<<4096, 256, 0, stream>>>(wd,   wd_bf,   1048576);

  gemm_bt<1><<<dim3(17, 32), 256, 0, stream>>>(hs_bf, wqkv_bf, qkv_bf, TT, NQKV, HIDN);

  rope_kernel<<<2176, 256, 0, stream>>>(qkv_bf, cosb, sinb, q_bf, k_bf, vt_bf);

  attn_kernel<<<dim3(SS / 32, 4, BB), 512, 0, stream>>>(q_bf, k_bf, vt_bf, hs_bf);

  gemm_bt<0><<<dim3(16, 32), 256, 0, stream>>>(hs_bf, wd_bf, d_out, TT, HIDN, HIDN);
}

// Round 9
// 229.959 us; speedup vs baseline: 2.6152x; 1.0755x over previous
//
#include <hip/hip_runtime.h>

// Problem constants
#define BB   2
#define SS   2048
#define TT   4096      // B*S
#define HH   32
#define DD   64
#define HIDN 2048      // H*D
#define NQKV 2176      // (H+2)*D
#define QK_SCALE_LOG2 0.1803368801f   // 0.125 * log2(e): scores in log2 domain

#define AS1 __attribute__((address_space(1)))
#define AS3 __attribute__((address_space(3)))

typedef __attribute__((ext_vector_type(8))) short short8;
typedef __attribute__((ext_vector_type(4))) float f32x4;
typedef __attribute__((ext_vector_type(16))) float f32x16;
typedef __attribute__((ext_vector_type(4))) unsigned short ushort4_t;
typedef __attribute__((ext_vector_type(4))) unsigned int uint4_t;

__device__ inline unsigned short f2bf(float f) {
  unsigned int u = __builtin_bit_cast(unsigned int, f);
  u += 0x7FFFu + ((u >> 16) & 1u);   // round-to-nearest-even
  return (unsigned short)(u >> 16);
}
__device__ inline float bf2f(unsigned short s) {
  unsigned int u = ((unsigned int)s) << 16;
  return __builtin_bit_cast(float, u);
}
__device__ inline float exp2fast(float x) { return __builtin_amdgcn_exp2f(x); }

// ---------------------------------------------------------------- f32 -> bf16
__global__ __launch_bounds__(256)
void cvt_kernel(const float* __restrict__ in, unsigned short* __restrict__ out, int n4) {
  int i = blockIdx.x * 256 + threadIdx.x;
  if (i >= n4) return;
  float4 v = ((const float4*)in)[i];
  ushort4_t u = { f2bf(v.x), f2bf(v.y), f2bf(v.z), f2bf(v.w) };
  *(ushort4_t*)(out + (long)i * 4) = u;
}

// ------------------------------------------------- C = A(MxK) * B(NxK)^T GEMM
template<int OUT_BF16>
__global__ __launch_bounds__(256)
void gemm_bt(const unsigned short* __restrict__ A, const unsigned short* __restrict__ Bw,
             void* __restrict__ Cp, int M, int N, int K) {
  __shared__ unsigned short lA[128 * 32];
  __shared__ unsigned short lB[128 * 32];
  const int tid  = threadIdx.x;
  const int lane = tid & 63;
  const int wv   = tid >> 6;
  const int wr   = wv >> 1, wc = wv & 1;
  const int g    = lane >> 4, qq = lane & 15;
  const long bm0 = (long)blockIdx.y * 128;
  const long bn0 = (long)blockIdx.x * 128;
  const int srow  = tid >> 2;          // staging row 0..63
  const int skoff = (tid & 3) << 3;    // k offset (ushorts)

  f32x4 zero = {0.f, 0.f, 0.f, 0.f};
  f32x4 acc[4][4];
#pragma unroll
  for (int m = 0; m < 4; ++m)
#pragma unroll
    for (int n = 0; n < 4; ++n) acc[m][n] = zero;

  const unsigned short* aSrc = A  + (bm0 + srow) * K + skoff;
  const unsigned short* bSrc = Bw + (bn0 + srow) * K + skoff;

  for (int k0 = 0; k0 < K; k0 += 32) {
    __syncthreads();   // previous tile's compute done before overwrite
    __builtin_amdgcn_global_load_lds(
        (const AS1 unsigned int*)(aSrc + k0),
        (AS3 unsigned int*)(lA + wv * 512), 16, 0, 0);
    __builtin_amdgcn_global_load_lds(
        (const AS1 unsigned int*)(aSrc + (long)64 * K + k0),
        (AS3 unsigned int*)(lA + 2048 + wv * 512), 16, 0, 0);
    __builtin_amdgcn_global_load_lds(
        (const AS1 unsigned int*)(bSrc + k0),
        (AS3 unsigned int*)(lB + wv * 512), 16, 0, 0);
    __builtin_amdgcn_global_load_lds(
        (const AS1 unsigned int*)(bSrc + (long)64 * K + k0),
        (AS3 unsigned int*)(lB + 2048 + wv * 512), 16, 0, 0);
    __syncthreads();   // drains vmcnt -> staged data visible

    short8 af[4], bf[4];
#pragma unroll
    for (int m = 0; m < 4; ++m)
      af[m] = *(const short8*)&lA[(wr * 64 + m * 16 + qq) * 32 + g * 8];
#pragma unroll
    for (int n = 0; n < 4; ++n)
      bf[n] = *(const short8*)&lB[(wc * 64 + n * 16 + qq) * 32 + g * 8];
#pragma unroll
    for (int m = 0; m < 4; ++m)
#pragma unroll
      for (int n = 0; n < 4; ++n)
        acc[m][n] = __builtin_amdgcn_mfma_f32_16x16x32_bf16(af[m], bf[n], acc[m][n], 0, 0, 0);
  }

  // epilogue: C/D layout col=lane&15, row=(lane>>4)*4+reg
#pragma unroll
  for (int m = 0; m < 4; ++m) {
#pragma unroll
    for (int r = 0; r < 4; ++r) {
      long row = bm0 + wr * 64 + m * 16 + g * 4 + r;
#pragma unroll
      for (int n = 0; n < 4; ++n) {
        long col = bn0 + wc * 64 + n * 16 + qq;
        float v = acc[m][n][r];
        if (OUT_BF16) ((unsigned short*)Cp)[row * N + col] = f2bf(v);
        else          ((float*)Cp)[row * N + col] = v;
      }
    }
  }
}

// --------------------------------------------------------- RoPE + split + V^T
// Vectorized (short8): one thread per (t, head34, octet-of-8). q heads get
// RoPE + QK_SCALE*log2(e) (attn softmax runs in exp2 domain); k head RoPE;
// v head scattered into tiled-transposed [B][S/64 tiles][64 d][64 s].
__global__ __launch_bounds__(256)
void rope_kernel(const unsigned short* __restrict__ qkv, const float* __restrict__ cosb,
                 const float* __restrict__ sinb, unsigned short* __restrict__ q_out,
                 unsigned short* __restrict__ k_out, unsigned short* __restrict__ v_out) {
  int idx = blockIdx.x * 256 + threadIdx.x;
  if (idx >= TT * 136) return;           // 34 heads * 4 octets
  int t   = idx / 136;
  int rem = idx - t * 136;
  int hh  = rem >> 2;
  int i0  = (rem & 3) * 8;
  const unsigned short* row = qkv + (long)t * NQKV;

  if (hh < 33) {                         // rope path (q heads + k head)
    const unsigned short* src = row + (hh < 32 ? hh * 64 : 2048);
    short8 a = *(const short8*)(src + i0);
    short8 b = *(const short8*)(src + 32 + i0);
    float cv[8], sv[8];
    *(float4*)(cv)     = *(const float4*)(cosb + t * 32 + i0);
    *(float4*)(cv + 4) = *(const float4*)(cosb + t * 32 + i0 + 4);
    *(float4*)(sv)     = *(const float4*)(sinb + t * 32 + i0);
    *(float4*)(sv + 4) = *(const float4*)(sinb + t * 32 + i0 + 4);
    const float sc = (hh < 32) ? QK_SCALE_LOG2 : 1.f;
    short8 ra, rb;
#pragma unroll
    for (int j = 0; j < 8; ++j) {
      float x1 = bf2f((unsigned short)a[j]);
      float x2 = bf2f((unsigned short)b[j]);
      ra[j] = (short)f2bf((x1 * cv[j] - x2 * sv[j]) * sc);
      rb[j] = (short)f2bf((x2 * cv[j] + x1 * sv[j]) * sc);
    }
    unsigned short* dst = (hh < 32) ? q_out + ((long)t * 32 + hh) * 64
                                    : k_out + (long)t * 64;
    *(short8*)(dst + i0)      = ra;
    *(short8*)(dst + 32 + i0) = rb;
  } else {                               // v head -> tiled transpose scatter
    const unsigned short* src = row + 2112;
    short8 a = *(const short8*)(src + i0);
    short8 b = *(const short8*)(src + 32 + i0);
    int bb = t >> 11, s = t & 2047;
    int tile = s >> 6, c = s & 63;
    long base = ((long)bb * 32 + tile) * 64;   // row units (rows of 64 ushorts)
#pragma unroll
    for (int j = 0; j < 8; ++j) {
      v_out[(base + i0 + j) * 64 + c]      = (unsigned short)a[j];
      v_out[(base + 32 + i0 + j) * 64 + c] = (unsigned short)b[j];
    }
  }
}

// -------------------------------------------------------------- flash attention
// Block = 4 waves = 4 heads at the same (b, q-tile); MQA => waves share K/V.
// Grid (64,8,2)=1024 blocks -> ~4 blocks/CU (4 waves/SIMD) for latency hiding.
// KVBLK=128 staged per barrier pair (K 16KB + two 8KB V^T tiles = 32KB LDS),
// two 64-kv compute phases per stage.
// PROVEN two-barrier skeleton (rounds 4/6/7, post-timing validated):
//   per iter: barrier -> issue global_load_lds -> barrier (drains) -> compute.
// No memory ops in flight across barriers (sync skeleton frozen; overlapped
// variants raced under graph replay in rounds 3/5).
// Tiles are [rows][128 B] with XOR swizzle sigma(row)=(row&7)<<4 both-sides.
// Per wave: swapped QK^T (S^T = mfma(K,Q), lane owns q=lane&31), lane-local
// online softmax in exp2 domain (scores pre-scaled by log2e), defer-max THR=8.
// P^T -> B-frags via v_cvt_pk_bf16_f32 + v_permlane32_swap_b32 (T12): after
// swap(a0,a2), swap(a1,a3) the fragment is literally {a0,a1,a2,a3}.
// O^T = V^T * P^T. s_setprio(1) around MFMA clusters (T5).
__global__ __launch_bounds__(256, 4)
void attn_kernel(const unsigned short* __restrict__ qs, const unsigned short* __restrict__ kr,
                 const unsigned short* __restrict__ vt, unsigned short* __restrict__ ob) {
  __shared__ unsigned char lsm[32768];   // K rows 0-127 (16KB) | V0 | V1 (8KB each)
  const int tid  = threadIdx.x;
  const int lane = tid & 63;
  const int wv   = tid >> 6;          // 0..3
  const int half = lane >> 5;
  const int qc   = lane & 31;
  const int h    = blockIdx.y * 4 + wv;
  const int b    = blockIdx.z;
  const int qt   = (SS / 32 - 1) - blockIdx.x;   // biggest triangles first
  const int q0   = qt * 32;
  const int nb   = (q0 >> 7) + 1;                // 128-kv blocks

  const unsigned short* kb  = kr + (long)b * SS * 64;
  const unsigned short* vtb = vt + (long)b * (SS / 64) * 64 * 64;

  // ---- staging: 8 gloads/thread (4 K + 4 V sweeps of 32 rows each);
  // thread owns row (tid>>3)+32g, 16B at linear col (tid&7)*16;
  // global source col inverse-swizzled (ushort units).
  const int srow = tid >> 3;                                       // 0..31
  const int scol = ((((tid & 7) << 4) ^ ((srow & 7) << 4)) >> 1);  // ushorts

  // ---- swizzled LDS read offsets within a [64 rows][128B] subtile.
  const int rswz = (qc & 7) << 4;
  int roff[4];
#pragma unroll
  for (int i = 0; i < 4; ++i)
    roff[i] = qc * 128 + ((i * 32 + half * 16) ^ rswz);

  // ---- Q B-fragments: lane holds q-row q0+qc, k(=d) = dstep*16 + half*8 + j
  short8 qf[4];
  const unsigned short* qrow = qs + ((long)(b * SS + q0 + qc) * HH + h) * 64;
#pragma unroll
  for (int dstep = 0; dstep < 4; ++dstep)
    qf[dstep] = *(const short8*)(qrow + dstep * 16 + half * 8);

  f32x16 o0, o1;                       // O^T accum: d in [0,32) and [32,64)
#pragma unroll
  for (int r = 0; r < 16; ++r) { o0[r] = 0.f; o1[r] = 0.f; }
  float mst = -1e30f, lst = 0.f;

  for (int ib = 0; ib < nb; ++ib) {
    const int kv0   = ib * 128;
    const int lastt = (ib == nb - 1);
    __syncthreads();                   // all waves done reading previous tile
    {
      const unsigned short* kS = kb + ((long)(kv0 + srow)) * 64 + scol;
#pragma unroll
      for (int g = 0; g < 4; ++g)
        __builtin_amdgcn_global_load_lds((const AS1 unsigned int*)(kS + g * 32 * 64),
            (AS3 unsigned int*)(lsm + g * 4096 + wv * 1024), 16, 0, 0);
      const unsigned short* vS = vtb + (long)(2 * ib) * 4096 + srow * 64 + scol;
#pragma unroll
      for (int g = 0; g < 4; ++g)
        __builtin_amdgcn_global_load_lds((const AS1 unsigned int*)(vS + g * 32 * 64),
            (AS3 unsigned int*)(lsm + 16384 + g * 4096 + wv * 1024), 16, 0, 0);
    }
    __syncthreads();                   // drains vmcnt -> staged data visible

    for (int ph = 0; ph < 2; ++ph) {
      if (ph && lastt && (q0 & 127) < 64) break;   // phase B fully masked
      const unsigned char* Kb = lsm + ph * 8192;
      const unsigned char* Vb = lsm + 16384 + ph * 8192;
      const int kvb = kv0 + ph * 64;

      // ---- QK^T: S^T[kv][q], kv kvb+[0,32) -> st0, kvb+[32,64) -> st1
      f32x16 st0, st1;
#pragma unroll
      for (int r = 0; r < 16; ++r) { st0[r] = 0.f; st1[r] = 0.f; }
      __builtin_amdgcn_s_setprio(1);
#pragma unroll
      for (int dstep = 0; dstep < 4; ++dstep) {
        short8 kfA = *(const short8*)(Kb + roff[dstep]);
        short8 kfB = *(const short8*)(Kb + roff[dstep] + 4096);
        st0 = __builtin_amdgcn_mfma_f32_32x32x16_bf16(kfA, qf[dstep], st0, 0, 0, 0);
        st1 = __builtin_amdgcn_mfma_f32_32x32x16_bf16(kfB, qf[dstep], st1, 0, 0, 0);
      }
      __builtin_amdgcn_s_setprio(0);
      if (lastt) {                     // causal mask (only last tile partial)
#pragma unroll
        for (int r = 0; r < 16; ++r) {
          int rkv = (r & 3) + 8 * (r >> 2) + 4 * half;
          if (kvb + rkv      > q0 + qc) st0[r] = -1e30f;
          if (kvb + 32 + rkv > q0 + qc) st1[r] = -1e30f;
        }
      }
      // ---- online softmax, exp2 domain (state per q = lane-local), defer THR=8
      float pmax = st0[0];
#pragma unroll
      for (int r = 1; r < 16; ++r) pmax = fmaxf(pmax, st0[r]);
#pragma unroll
      for (int r = 0; r < 16; ++r) pmax = fmaxf(pmax, st1[r]);
      pmax = fmaxf(pmax, __shfl_xor(pmax, 32));
      if (!__all(pmax - mst <= 8.f)) {
        const float mnew = fmaxf(mst, pmax);
        const float scal = exp2fast(mst - mnew);
        lst *= scal;
#pragma unroll
        for (int r = 0; r < 16; ++r) { o0[r] *= scal; o1[r] *= scal; }
        mst = mnew;
      }
      float psum = 0.f;
#pragma unroll
      for (int r = 0; r < 16; ++r) { st0[r] = exp2fast(st0[r] - mst); psum += st0[r]; }
#pragma unroll
      for (int r = 0; r < 16; ++r) { st1[r] = exp2fast(st1[r] - mst); psum += st1[r]; }
      psum += __shfl_xor(psum, 32);
      lst += psum;

      // ---- P^T -> B-fragments via cvt_pk + permlane32_swap (T12).
      // kv rows at this lane: (r&3) + 8*(r>>2) + 4*half [+32 for st1].
      // After swap(a0,a2),swap(a1,a3): frag = {a0,a1,a2,a3}.
      short8 pb[4];
#pragma unroll
      for (int hseg = 0; hseg < 2; ++hseg) {
        const f32x16& pp = hseg ? st1 : st0;
        unsigned int a0, a1, a2, a3, a4, a5, a6, a7;
        asm("v_cvt_pk_bf16_f32 %0, %1, %2" : "=v"(a0) : "v"(pp[0]),  "v"(pp[1]));
        asm("v_cvt_pk_bf16_f32 %0, %1, %2" : "=v"(a1) : "v"(pp[2]),  "v"(pp[3]));
        asm("v_cvt_pk_bf16_f32 %0, %1, %2" : "=v"(a2) : "v"(pp[4]),  "v"(pp[5]));
        asm("v_cvt_pk_bf16_f32 %0, %1, %2" : "=v"(a3) : "v"(pp[6]),  "v"(pp[7]));
        asm("v_cvt_pk_bf16_f32 %0, %1, %2" : "=v"(a4) : "v"(pp[8]),  "v"(pp[9]));
        asm("v_cvt_pk_bf16_f32 %0, %1, %2" : "=v"(a5) : "v"(pp[10]), "v"(pp[11]));
        asm("v_cvt_pk_bf16_f32 %0, %1, %2" : "=v"(a6) : "v"(pp[12]), "v"(pp[13]));
        asm("v_cvt_pk_bf16_f32 %0, %1, %2" : "=v"(a7) : "v"(pp[14]), "v"(pp[15]));
        asm("v_permlane32_swap_b32 %0, %1" : "+v"(a0), "+v"(a2));
        asm("v_permlane32_swap_b32 %0, %1" : "+v"(a1), "+v"(a3));
        asm("v_permlane32_swap_b32 %0, %1" : "+v"(a4), "+v"(a6));
        asm("v_permlane32_swap_b32 %0, %1" : "+v"(a5), "+v"(a7));
        uint4_t w0 = { a0, a1, a2, a3 };   // kv seg+[0,16)
        uint4_t w1 = { a4, a5, a6, a7 };   // kv seg+[16,32)
        pb[hseg * 2]     = __builtin_bit_cast(short8, w0);
        pb[hseg * 2 + 1] = __builtin_bit_cast(short8, w1);
      }

      // ---- PV: O^T[d][q] += V^T[d][kv] * P^T[kv][q]  (4 ksteps of 16 kv)
      __builtin_amdgcn_s_setprio(1);
#pragma unroll
      for (int ks = 0; ks < 4; ++ks) {
        short8 vfA = *(const short8*)(Vb + roff[ks]);
        short8 vfB = *(const short8*)(Vb + roff[ks] + 4096);
        o0 = __builtin_amdgcn_mfma_f32_32x32x16_bf16(vfA, pb[ks], o0, 0, 0, 0);
        o1 = __builtin_amdgcn_mfma_f32_32x32x16_bf16(vfB, pb[ks], o1, 0, 0, 0);
      }
      __builtin_amdgcn_s_setprio(0);
    }
  }

  // ---- finalize: O[q][d] = O^T[d][q] / l;  q = qc (lane-local l state)
  const float inv = 1.f / lst;
  unsigned short* orow = ob + ((long)(b * SS + q0 + qc) * HH + h) * 64;
#pragma unroll
  for (int r = 0; r < 16; ++r) {
    int d0 = (r & 3) + 8 * (r >> 2) + 4 * half;
    orow[d0]      = f2bf(o0[r] * inv);
    orow[32 + d0] = f2bf(o1[r] * inv);
  }
}

// ------------------------------------------------------------------- launcher
extern "C" void kernel_launch(void* const* d_in, const int* in_sizes, int n_in,
                              void* d_out, int out_size, void* d_ws, size_t ws_size,
                              hipStream_t stream) {
  const float* hs   = (const float*)d_in[0];
  const float* cosb = (const float*)d_in[1];
  const float* sinb = (const float*)d_in[2];
  const float* wqkv = (const float*)d_in[3];
  const float* wd   = (const float*)d_in[4];

  char* ws = (char*)d_ws;
  // hs_bf region (16 MB) is reused as the attention-output bf16 buffer:
  // hidden is fully consumed by the QKV GEMM before attn writes it.
  unsigned short* hs_bf   = (unsigned short*)(ws);
  unsigned short* wqkv_bf = (unsigned short*)(ws + 16777216);
  unsigned short* wd_bf   = (unsigned short*)(ws + 25690112);
  unsigned short* qkv_bf  = (unsigned short*)(ws + 34078720);
  unsigned short* q_bf    = (unsigned short*)(ws + 51904512);
  unsigned short* k_bf    = (unsigned short*)(ws + 68681728);
  unsigned short* vt_bf   = (unsigned short*)(ws + 69206016);

  cvt_kernel<<<8192, 256, 0, stream>>>(hs,   hs_bf,   2097152);
  cvt_kernel<<<4352, 256, 0, stream>>>(wqkv, wqkv_bf, 1114112);
  cvt_kernel<<<4096, 256, 0, stream>>>(wd,   wd_bf,   1048576);

  gemm_bt<1><<<dim3(17, 32), 256, 0, stream>>>(hs_bf, wqkv_bf, qkv_bf, TT, NQKV, HIDN);

  rope_kernel<<<2176, 256, 0, stream>>>(qkv_bf, cosb, sinb, q_bf, k_bf, vt_bf);

  attn_kernel<<<dim3(SS / 32, 8, BB), 256, 0, stream>>>(q_bf, k_bf, vt_bf, hs_bf);

  gemm_bt<0><<<dim3(16, 32), 256, 0, stream>>>(hs_bf, wd_bf, d_out, TT, HIDN, HIDN);
}

// Round 10
// 184.297 us; speedup vs baseline: 3.2631x; 1.2478x over previous
//
#include <hip/hip_runtime.h>

// Problem constants
#define BB   2
#define SS   2048
#define TT   4096      // B*S
#define HH   32
#define DD   64
#define HIDN 2048      // H*D
#define NQKV 2176      // (H+2)*D
#define QK_SCALE_LOG2 0.1803368801f   // 0.125 * log2(e): scores in log2 domain

#define AS1 __attribute__((address_space(1)))
#define AS3 __attribute__((address_space(3)))

typedef __attribute__((ext_vector_type(8))) short short8;
typedef __attribute__((ext_vector_type(4))) float f32x4;
typedef __attribute__((ext_vector_type(16))) float f32x16;
typedef __attribute__((ext_vector_type(4))) unsigned short ushort4_t;
typedef __attribute__((ext_vector_type(4))) unsigned int uint4_t;

__device__ inline unsigned short f2bf(float f) {
  unsigned int u = __builtin_bit_cast(unsigned int, f);
  u += 0x7FFFu + ((u >> 16) & 1u);   // round-to-nearest-even
  return (unsigned short)(u >> 16);
}
__device__ inline float bf2f(unsigned short s) {
  unsigned int u = ((unsigned int)s) << 16;
  return __builtin_bit_cast(float, u);
}
__device__ inline float exp2fast(float x) { return __builtin_amdgcn_exp2f(x); }

// ---------------------------------------------------------------- f32 -> bf16
__global__ __launch_bounds__(256)
void cvt_kernel(const float* __restrict__ in, unsigned short* __restrict__ out, int n4) {
  int i = blockIdx.x * 256 + threadIdx.x;
  if (i >= n4) return;
  float4 v = ((const float4*)in)[i];
  ushort4_t u = { f2bf(v.x), f2bf(v.y), f2bf(v.z), f2bf(v.w) };
  *(ushort4_t*)(out + (long)i * 4) = u;
}

// ------------------------------------------------- C = A(MxK) * B(NxK)^T GEMM
// 128x128 tile, BK=64, 4 waves of 64x64. LDS tiles [128 rows][128 B] with XOR
// swizzle sigma(row)=(row&7)<<4 both-sides (pre-swizzled global source col +
// swizzled ds_read col) -> conflict-free b128 reads (old 64B-row layout was an
// 8-way bank conflict). Two-barrier skeleton per BK step (proven race-free).
template<int OUT_BF16>
__global__ __launch_bounds__(256)
void gemm_bt(const unsigned short* __restrict__ A, const unsigned short* __restrict__ Bw,
             void* __restrict__ Cp, int M, int N, int K) {
  __shared__ unsigned char lAB[32768];   // A [128][128B] | B [128][128B]
  const int tid  = threadIdx.x;
  const int lane = tid & 63;
  const int wv   = tid >> 6;
  const int wr   = wv >> 1, wc = wv & 1;
  const int g    = lane >> 4, qq = lane & 15;
  const long bm0 = (long)blockIdx.y * 128;
  const long bn0 = (long)blockIdx.x * 128;
  const int srow  = tid >> 3;                                      // 0..31
  const int scolu = ((((tid & 7) << 4) ^ ((srow & 7) << 4)) >> 1); // ushorts

  f32x4 zero = {0.f, 0.f, 0.f, 0.f};
  f32x4 acc[4][4];
#pragma unroll
  for (int m = 0; m < 4; ++m)
#pragma unroll
    for (int n = 0; n < 4; ++n) acc[m][n] = zero;

  const unsigned short* aSrc = A  + (bm0 + srow) * K + scolu;
  const unsigned short* bSrc = Bw + (bn0 + srow) * K + scolu;
  const int rswz = (qq & 7) << 4;

  for (int k0 = 0; k0 < K; k0 += 64) {
    __syncthreads();   // previous tile's compute done before overwrite
#pragma unroll
    for (int gg = 0; gg < 4; ++gg) {
      __builtin_amdgcn_global_load_lds(
          (const AS1 unsigned int*)(aSrc + k0 + (long)32 * gg * K),
          (AS3 unsigned int*)(lAB + gg * 4096 + wv * 1024), 16, 0, 0);
      __builtin_amdgcn_global_load_lds(
          (const AS1 unsigned int*)(bSrc + k0 + (long)32 * gg * K),
          (AS3 unsigned int*)(lAB + 16384 + gg * 4096 + wv * 1024), 16, 0, 0);
    }
    __syncthreads();   // drains vmcnt -> staged data visible

#pragma unroll
    for (int ks = 0; ks < 2; ++ks) {
      short8 af[4], bf[4];
#pragma unroll
      for (int m = 0; m < 4; ++m)
        af[m] = *(const short8*)(lAB + (wr * 64 + m * 16 + qq) * 128
                                     + ((ks * 64 + g * 16) ^ rswz));
#pragma unroll
      for (int n = 0; n < 4; ++n)
        bf[n] = *(const short8*)(lAB + 16384 + (wc * 64 + n * 16 + qq) * 128
                                     + ((ks * 64 + g * 16) ^ rswz));
#pragma unroll
      for (int m = 0; m < 4; ++m)
#pragma unroll
        for (int n = 0; n < 4; ++n)
          acc[m][n] = __builtin_amdgcn_mfma_f32_16x16x32_bf16(af[m], bf[n], acc[m][n], 0, 0, 0);
    }
  }

  // epilogue: C/D layout col=lane&15, row=(lane>>4)*4+reg
#pragma unroll
  for (int m = 0; m < 4; ++m) {
#pragma unroll
    for (int r = 0; r < 4; ++r) {
      long row = bm0 + wr * 64 + m * 16 + g * 4 + r;
#pragma unroll
      for (int n = 0; n < 4; ++n) {
        long col = bn0 + wc * 64 + n * 16 + qq;
        float v = acc[m][n][r];
        if (OUT_BF16) ((unsigned short*)Cp)[row * N + col] = f2bf(v);
        else          ((float*)Cp)[row * N + col] = v;
      }
    }
  }
}

// --------------------------------------------------------- RoPE + split + V^T
// Vectorized (short8): one thread per (t, head34, octet-of-8). q heads get
// RoPE + QK_SCALE*log2(e) (attn softmax runs in exp2 domain); k head RoPE;
// v head scattered into tiled-transposed [B][S/64 tiles][64 d][64 s].
__global__ __launch_bounds__(256)
void rope_kernel(const unsigned short* __restrict__ qkv, const float* __restrict__ cosb,
                 const float* __restrict__ sinb, unsigned short* __restrict__ q_out,
                 unsigned short* __restrict__ k_out, unsigned short* __restrict__ v_out) {
  int idx = blockIdx.x * 256 + threadIdx.x;
  if (idx >= TT * 136) return;           // 34 heads * 4 octets
  int t   = idx / 136;
  int rem = idx - t * 136;
  int hh  = rem >> 2;
  int i0  = (rem & 3) * 8;
  const unsigned short* row = qkv + (long)t * NQKV;

  if (hh < 33) {                         // rope path (q heads + k head)
    const unsigned short* src = row + (hh < 32 ? hh * 64 : 2048);
    short8 a = *(const short8*)(src + i0);
    short8 b = *(const short8*)(src + 32 + i0);
    float cv[8], sv[8];
    *(float4*)(cv)     = *(const float4*)(cosb + t * 32 + i0);
    *(float4*)(cv + 4) = *(const float4*)(cosb + t * 32 + i0 + 4);
    *(float4*)(sv)     = *(const float4*)(sinb + t * 32 + i0);
    *(float4*)(sv + 4) = *(const float4*)(sinb + t * 32 + i0 + 4);
    const float sc = (hh < 32) ? QK_SCALE_LOG2 : 1.f;
    short8 ra, rb;
#pragma unroll
    for (int j = 0; j < 8; ++j) {
      float x1 = bf2f((unsigned short)a[j]);
      float x2 = bf2f((unsigned short)b[j]);
      ra[j] = (short)f2bf((x1 * cv[j] - x2 * sv[j]) * sc);
      rb[j] = (short)f2bf((x2 * cv[j] + x1 * sv[j]) * sc);
    }
    unsigned short* dst = (hh < 32) ? q_out + ((long)t * 32 + hh) * 64
                                    : k_out + (long)t * 64;
    *(short8*)(dst + i0)      = ra;
    *(short8*)(dst + 32 + i0) = rb;
  } else {                               // v head -> tiled transpose scatter
    const unsigned short* src = row + 2112;
    short8 a = *(const short8*)(src + i0);
    short8 b = *(const short8*)(src + 32 + i0);
    int bb = t >> 11, s = t & 2047;
    int tile = s >> 6, c = s & 63;
    long base = ((long)bb * 32 + tile) * 64;   // row units (rows of 64 ushorts)
#pragma unroll
    for (int j = 0; j < 8; ++j) {
      v_out[(base + i0 + j) * 64 + c]      = (unsigned short)a[j];
      v_out[(base + 32 + i0 + j) * 64 + c] = (unsigned short)b[j];
    }
  }
}

// -------------------------------------------------------------- flash attention
// CAUSAL LOAD-BALANCED PAIRING: block x in [0,32) handles q-tiles qtA=x (small)
// and qtB=63-x (big) for 4 heads (one per wave) -> every block has ~uniform
// work (nbA+nbB ~ 17 phase-units), and the K/V tiles staged for qtB are reused
// by qtA (its kv range is a subset) -> ~26% less staging traffic.
// Grid (32,8,2)=512 blocks, 2 blocks/CU.
// KVBLK=128 staged per barrier pair (K 16KB + two 8KB V^T tiles = 32KB LDS),
// two 64-kv compute phases per stage; per phase both q-states computed.
// PROVEN two-barrier skeleton (rounds 4/6/7/9, post-timing validated):
//   per iter: barrier -> issue global_load_lds -> barrier (drains) -> compute.
// Tiles [rows][128 B], XOR swizzle sigma(row)=(row&7)<<4 both-sides.
// Per state: swapped QK^T (S^T = mfma(K,Q), lane owns q=lane&31), lane-local
// online softmax in exp2 domain, defer-max THR=8, P^T via v_cvt_pk_bf16_f32 +
// v_permlane32_swap_b32, O^T = V^T * P^T. s_setprio(1) around MFMA clusters.
__global__ __launch_bounds__(256, 2)
void attn_kernel(const unsigned short* __restrict__ qs, const unsigned short* __restrict__ kr,
                 const unsigned short* __restrict__ vt, unsigned short* __restrict__ ob) {
  __shared__ unsigned char lsm[32768];   // K rows 0-127 (16KB) | V0 | V1 (8KB each)
  const int tid  = threadIdx.x;
  const int lane = tid & 63;
  const int wv   = tid >> 6;          // 0..3
  const int half = lane >> 5;
  const int qc   = lane & 31;
  const int h    = blockIdx.y * 4 + wv;
  const int b    = blockIdx.z;
  const int qtA  = blockIdx.x;                   // small triangle
  const int qtB  = (SS / 32 - 1) - blockIdx.x;   // big triangle
  const int q0A  = qtA * 32, q0B = qtB * 32;
  const int nbA  = (q0A >> 7) + 1, nbB = (q0B >> 7) + 1;   // 128-kv blocks

  const unsigned short* kb  = kr + (long)b * SS * 64;
  const unsigned short* vtb = vt + (long)b * (SS / 64) * 64 * 64;

  // ---- staging: thread owns row (tid>>3)+32g, 16B at linear col (tid&7)*16;
  // global source col inverse-swizzled (ushort units).
  const int srow = tid >> 3;                                       // 0..31
  const int scol = ((((tid & 7) << 4) ^ ((srow & 7) << 4)) >> 1);  // ushorts

  // ---- swizzled LDS read offsets within a [64 rows][128B] subtile.
  const int rswz = (qc & 7) << 4;
  int roff[4];
#pragma unroll
  for (int i = 0; i < 4; ++i)
    roff[i] = qc * 128 + ((i * 32 + half * 16) ^ rswz);

  // ---- Q B-fragments for both states: lane holds q-row q0+qc
  short8 qfA[4], qfB[4];
  {
    const unsigned short* qrA = qs + ((long)(b * SS + q0A + qc) * HH + h) * 64;
    const unsigned short* qrB = qs + ((long)(b * SS + q0B + qc) * HH + h) * 64;
#pragma unroll
    for (int dstep = 0; dstep < 4; ++dstep) {
      qfA[dstep] = *(const short8*)(qrA + dstep * 16 + half * 8);
      qfB[dstep] = *(const short8*)(qrB + dstep * 16 + half * 8);
    }
  }

  f32x16 oA0, oA1, oB0, oB1;
#pragma unroll
  for (int r = 0; r < 16; ++r) { oA0[r] = 0.f; oA1[r] = 0.f; oB0[r] = 0.f; oB1[r] = 0.f; }
  float mA = -1e30f, lA = 0.f, mB = -1e30f, lB = 0.f;

// One 64-kv phase for one q-state (macro: unique scope per expansion).
#define PHASE(qf, o0, o1, mst, lst, q0x, isLast)                                 \
  do {                                                                           \
    f32x16 st0, st1;                                                             \
    _Pragma("unroll")                                                            \
    for (int r = 0; r < 16; ++r) { st0[r] = 0.f; st1[r] = 0.f; }                 \
    __builtin_amdgcn_s_setprio(1);                                               \
    _Pragma("unroll")                                                            \
    for (int dstep = 0; dstep < 4; ++dstep) {                                    \
      short8 kfA_ = *(const short8*)(Kb + roff[dstep]);                          \
      short8 kfB_ = *(const short8*)(Kb + roff[dstep] + 4096);                   \
      st0 = __builtin_amdgcn_mfma_f32_32x32x16_bf16(kfA_, qf[dstep], st0, 0, 0, 0); \
      st1 = __builtin_amdgcn_mfma_f32_32x32x16_bf16(kfB_, qf[dstep], st1, 0, 0, 0); \
    }                                                                            \
    __builtin_amdgcn_s_setprio(0);                                               \
    if (isLast) {                                                                \
      _Pragma("unroll")                                                          \
      for (int r = 0; r < 16; ++r) {                                             \
        int rkv = (r & 3) + 8 * (r >> 2) + 4 * half;                             \
        if (kvb + rkv      > (q0x) + qc) st0[r] = -1e30f;                        \
        if (kvb + 32 + rkv > (q0x) + qc) st1[r] = -1e30f;                        \
      }                                                                          \
    }                                                                            \
    float pmax = st0[0];                                                         \
    _Pragma("unroll")                                                            \
    for (int r = 1; r < 16; ++r) pmax = fmaxf(pmax, st0[r]);                     \
    _Pragma("unroll")                                                            \
    for (int r = 0; r < 16; ++r) pmax = fmaxf(pmax, st1[r]);                     \
    pmax = fmaxf(pmax, __shfl_xor(pmax, 32));                                    \
    if (!__all(pmax - mst <= 8.f)) {                                             \
      const float mnew = fmaxf(mst, pmax);                                       \
      const float scal = exp2fast(mst - mnew);                                   \
      lst *= scal;                                                               \
      _Pragma("unroll")                                                          \
      for (int r = 0; r < 16; ++r) { o0[r] *= scal; o1[r] *= scal; }             \
      mst = mnew;                                                                \
    }                                                                            \
    float psum = 0.f;                                                            \
    _Pragma("unroll")                                                            \
    for (int r = 0; r < 16; ++r) { st0[r] = exp2fast(st0[r] - mst); psum += st0[r]; } \
    _Pragma("unroll")                                                            \
    for (int r = 0; r < 16; ++r) { st1[r] = exp2fast(st1[r] - mst); psum += st1[r]; } \
    psum += __shfl_xor(psum, 32);                                                \
    lst += psum;                                                                 \
    short8 pb[4];                                                                \
    _Pragma("unroll")                                                            \
    for (int hseg = 0; hseg < 2; ++hseg) {                                       \
      const f32x16& pp = hseg ? st1 : st0;                                       \
      unsigned int a0, a1, a2, a3, a4, a5, a6, a7;                               \
      asm("v_cvt_pk_bf16_f32 %0, %1, %2" : "=v"(a0) : "v"(pp[0]),  "v"(pp[1]));  \
      asm("v_cvt_pk_bf16_f32 %0, %1, %2" : "=v"(a1) : "v"(pp[2]),  "v"(pp[3]));  \
      asm("v_cvt_pk_bf16_f32 %0, %1, %2" : "=v"(a2) : "v"(pp[4]),  "v"(pp[5]));  \
      asm("v_cvt_pk_bf16_f32 %0, %1, %2" : "=v"(a3) : "v"(pp[6]),  "v"(pp[7]));  \
      asm("v_cvt_pk_bf16_f32 %0, %1, %2" : "=v"(a4) : "v"(pp[8]),  "v"(pp[9]));  \
      asm("v_cvt_pk_bf16_f32 %0, %1, %2" : "=v"(a5) : "v"(pp[10]), "v"(pp[11])); \
      asm("v_cvt_pk_bf16_f32 %0, %1, %2" : "=v"(a6) : "v"(pp[12]), "v"(pp[13])); \
      asm("v_cvt_pk_bf16_f32 %0, %1, %2" : "=v"(a7) : "v"(pp[14]), "v"(pp[15])); \
      asm("v_permlane32_swap_b32 %0, %1" : "+v"(a0), "+v"(a2));                  \
      asm("v_permlane32_swap_b32 %0, %1" : "+v"(a1), "+v"(a3));                  \
      asm("v_permlane32_swap_b32 %0, %1" : "+v"(a4), "+v"(a6));                  \
      asm("v_permlane32_swap_b32 %0, %1" : "+v"(a5), "+v"(a7));                  \
      uint4_t w0 = { a0, a1, a2, a3 };                                           \
      uint4_t w1 = { a4, a5, a6, a7 };                                           \
      pb[hseg * 2]     = __builtin_bit_cast(short8, w0);                         \
      pb[hseg * 2 + 1] = __builtin_bit_cast(short8, w1);                         \
    }                                                                            \
    __builtin_amdgcn_s_setprio(1);                                               \
    _Pragma("unroll")                                                            \
    for (int ks = 0; ks < 4; ++ks) {                                             \
      short8 vfA_ = *(const short8*)(Vb + roff[ks]);                             \
      short8 vfB_ = *(const short8*)(Vb + roff[ks] + 4096);                      \
      o0 = __builtin_amdgcn_mfma_f32_32x32x16_bf16(vfA_, pb[ks], o0, 0, 0, 0);   \
      o1 = __builtin_amdgcn_mfma_f32_32x32x16_bf16(vfB_, pb[ks], o1, 0, 0, 0);   \
    }                                                                            \
    __builtin_amdgcn_s_setprio(0);                                               \
  } while (0)

  for (int ib = 0; ib < nbB; ++ib) {
    const int kv0 = ib * 128;
    __syncthreads();                   // all waves done reading previous tile
    {
      const unsigned short* kS = kb + ((long)(kv0 + srow)) * 64 + scol;
#pragma unroll
      for (int gg = 0; gg < 4; ++gg)
        __builtin_amdgcn_global_load_lds((const AS1 unsigned int*)(kS + gg * 32 * 64),
            (AS3 unsigned int*)(lsm + gg * 4096 + wv * 1024), 16, 0, 0);
      const unsigned short* vS = vtb + (long)(2 * ib) * 4096 + srow * 64 + scol;
#pragma unroll
      for (int gg = 0; gg < 4; ++gg)
        __builtin_amdgcn_global_load_lds((const AS1 unsigned int*)(vS + gg * 32 * 64),
            (AS3 unsigned int*)(lsm + 16384 + gg * 4096 + wv * 1024), 16, 0, 0);
    }
    __syncthreads();                   // drains vmcnt -> staged data visible

    for (int ph = 0; ph < 2; ++ph) {
      const unsigned char* Kb = lsm + ph * 8192;
      const unsigned char* Vb = lsm + 16384 + ph * 8192;
      const int kvb = kv0 + ph * 64;
      // state B (big triangle)
      if (!(ph && ib == nbB - 1 && (q0B & 127) < 64))
        PHASE(qfB, oB0, oB1, mB, lB, q0B, ib == nbB - 1);
      // state A (small triangle; kv range subset of B's)
      if (ib < nbA && !(ph && ib == nbA - 1 && (q0A & 127) < 64))
        PHASE(qfA, oA0, oA1, mA, lA, q0A, ib == nbA - 1);
    }
  }
#undef PHASE

  // ---- finalize both states: O[q][d] = O^T[d][q] / l;  q = qc
  {
    const float inv = 1.f / lA;
    unsigned short* orow = ob + ((long)(b * SS + q0A + qc) * HH + h) * 64;
#pragma unroll
    for (int r = 0; r < 16; ++r) {
      int d0 = (r & 3) + 8 * (r >> 2) + 4 * half;
      orow[d0]      = f2bf(oA0[r] * inv);
      orow[32 + d0] = f2bf(oA1[r] * inv);
    }
  }
  {
    const float inv = 1.f / lB;
    unsigned short* orow = ob + ((long)(b * SS + q0B + qc) * HH + h) * 64;
#pragma unroll
    for (int r = 0; r < 16; ++r) {
      int d0 = (r & 3) + 8 * (r >> 2) + 4 * half;
      orow[d0]      = f2bf(oB0[r] * inv);
      orow[32 + d0] = f2bf(oB1[r] * inv);
    }
  }
}

// ------------------------------------------------------------------- launcher
extern "C" void kernel_launch(void* const* d_in, const int* in_sizes, int n_in,
                              void* d_out, int out_size, void* d_ws, size_t ws_size,
                              hipStream_t stream) {
  const float* hs   = (const float*)d_in[0];
  const float* cosb = (const float*)d_in[1];
  const float* sinb = (const float*)d_in[2];
  const float* wqkv = (const float*)d_in[3];
  const float* wd   = (const float*)d_in[4];

  char* ws = (char*)d_ws;
  // hs_bf region (16 MB) is reused as the attention-output bf16 buffer:
  // hidden is fully consumed by the QKV GEMM before attn writes it.
  unsigned short* hs_bf   = (unsigned short*)(ws);
  unsigned short* wqkv_bf = (unsigned short*)(ws + 16777216);
  unsigned short* wd_bf   = (unsigned short*)(ws + 25690112);
  unsigned short* qkv_bf  = (unsigned short*)(ws + 34078720);
  unsigned short* q_bf    = (unsigned short*)(ws + 51904512);
  unsigned short* k_bf    = (unsigned short*)(ws + 68681728);
  unsigned short* vt_bf   = (unsigned short*)(ws + 69206016);

  cvt_kernel<<<8192, 256, 0, stream>>>(hs,   hs_bf,   2097152);
  cvt_kernel<<<4352, 256, 0, stream>>>(wqkv, wqkv_bf, 1114112);
  cvt_kernel<<<4096, 256, 0, stream>>>(wd,   wd_bf,   1048576);

  gemm_bt<1><<<dim3(17, 32), 256, 0, stream>>>(hs_bf, wqkv_bf, qkv_bf, TT, NQKV, HIDN);

  rope_kernel<<<2176, 256, 0, stream>>>(qkv_bf, cosb, sinb, q_bf, k_bf, vt_bf);

  attn_kernel<<<dim3(SS / 64, 8, BB), 256, 0, stream>>>(q_bf, k_bf, vt_bf, hs_bf);

  gemm_bt<0><<<dim3(16, 32), 256, 0, stream>>>(hs_bf, wd_bf, d_out, TT, HIDN, HIDN);
}